// Round 1
// baseline (12776.926 us; speedup 1.0000x reference)
//
#include <hip/hip_runtime.h>
#include <math.h>

#define H 128
#define TE 32
#define ECSTRIDE 388  // 384 cols + 4 pad: keeps float4 alignment, staggers banks

// ---------------- graph build ----------------

__global__ void count_kernel(const int* __restrict__ col, int E, int* __restrict__ cnt) {
    int e = blockIdx.x * blockDim.x + threadIdx.x;
    if (e < E) atomicAdd(&cnt[col[e]], 1);
}

__global__ void scan_kernel(const int* __restrict__ cnt, int N, int E,
                            int* __restrict__ col_start, int* __restrict__ cursor,
                            float* __restrict__ dinv) {
    __shared__ int buf[1024];
    int tid = threadIdx.x;
    int run = 0;
    for (int base = 0; base < N; base += 1024) {
        int i = base + tid;
        int v = (i < N) ? cnt[i] : 0;
        buf[tid] = v;
        __syncthreads();
        for (int off = 1; off < 1024; off <<= 1) {
            int t = buf[tid];
            if (tid >= off) t += buf[tid - off];
            __syncthreads();
            buf[tid] = t;
            __syncthreads();
        }
        int incl = buf[tid];
        int tot  = buf[1023];
        if (i < N) {
            int excl = run + incl - v;
            col_start[i] = excl;
            cursor[i]    = excl;
            dinv[i] = rsqrtf((float)(v + 1));  // +1 self-loop
        }
        run += tot;
        __syncthreads();
    }
    if (tid == 0) col_start[N] = E;
}

__global__ void scatter_kernel(const int* __restrict__ row, const int* __restrict__ col, int E,
                               int* __restrict__ cursor, int* __restrict__ csc_src) {
    int e = blockIdx.x * blockDim.x + threadIdx.x;
    if (e < E) {
        int c = col[e];
        int p = atomicAdd(&cursor[c], 1);
        csc_src[p] = row[e];
    }
}

// ---------------- node transform (h @ W) ----------------

__global__ void node_gemm_kernel(const float* __restrict__ hin, const float* __restrict__ W,
                                 int N, int K, float* __restrict__ out) {
    int t = blockIdx.x * blockDim.x + threadIdx.x;
    if (t >= N * H) return;
    int j = t & (H - 1);
    int i = t >> 7;
    const float* hr = hin + (size_t)i * K;
    float acc = 0.f;
    for (int k = 0; k < K; ++k) acc = fmaf(hr[k], W[k * H + j], acc);
    out[t] = acc;
}

// ---------------- GCN aggregation (gather over CSC) ----------------

__global__ void aggregate_kernel(const float* __restrict__ hw, const int* __restrict__ col_start,
                                 const int* __restrict__ csc_src, const float* __restrict__ dinv,
                                 const float* __restrict__ bias, float* __restrict__ out, int N) {
    int i = blockIdx.x;
    int j = threadIdx.x;
    int s0 = col_start[i], s1 = col_start[i + 1];
    float acc = 0.f;
    for (int p = s0; p < s1; ++p) {
        int s = csc_src[p];
        acc = fmaf(dinv[s], hw[(size_t)s * H + j], acc);
    }
    float di = dinv[i];
    float v = fmaf(di, acc, fmaf(di * di, hw[(size_t)i * H + j], bias[j]));
    out[(size_t)i * H + j] = fmaxf(v, 0.f);
}

// ---------------- fused edge-MLP + classifier + log_softmax ----------------

__device__ inline void fma4(float4& acc, float a, const float4 w) {
    acc.x = fmaf(a, w.x, acc.x);
    acc.y = fmaf(a, w.y, acc.y);
    acc.z = fmaf(a, w.z, acc.z);
    acc.w = fmaf(a, w.w, acc.w);
}

__global__ __launch_bounds__(256) void classifier_kernel(
    const float* __restrict__ h, const int* __restrict__ row, const int* __restrict__ col,
    const float* __restrict__ ea,
    const float* __restrict__ We1, const float* __restrict__ be1,
    const float* __restrict__ We2, const float* __restrict__ be2,
    const float* __restrict__ Wc1, const float* __restrict__ bc1,
    const float* __restrict__ Wc2, const float* __restrict__ bc2,
    const float* __restrict__ Wc3, const float* __restrict__ bc3,
    float* __restrict__ out, int E) {
    __shared__ __align__(16) float ec[TE][ECSTRIDE];
    __shared__ int rS[TE], cS[TE];
    int tid = threadIdx.x;
    int e0 = blockIdx.x * TE;

    if (tid < TE) {
        int e = e0 + tid;
        rS[tid] = (e < E) ? row[e] : 0;
        cS[tid] = (e < E) ? col[e] : 0;
    }
    __syncthreads();

    // Phase A: gather h[row], h[col] -> ec[i][0:256]
    for (int u = tid; u < TE * 256; u += 256) {
        int i = u >> 8, j = u & 255;
        const float* src = (j < 128) ? (h + (size_t)rS[i] * H + j)
                                     : (h + (size_t)cS[i] * H + (j - 128));
        ec[i][j] = *src;
    }

    int i  = tid >> 3;            // edge within tile (0..31)
    int j0 = (tid & 7) * 16;      // 16 consecutive output cols

    // Phase B: t = relu(ea @ We1 + be1) -> ec[i][256:384]
    {
        int e = e0 + i;
        float a0 = 0, a1 = 0, a2 = 0, a3 = 0;
        if (e < E) {
            a0 = ea[(size_t)e * 4 + 0];
            a1 = ea[(size_t)e * 4 + 1];
            a2 = ea[(size_t)e * 4 + 2];
            a3 = ea[(size_t)e * 4 + 3];
        }
        for (int jj = 0; jj < 16; ++jj) {
            int j = j0 + jj;
            float v = be1[j];
            v = fmaf(a0, We1[0 * H + j], v);
            v = fmaf(a1, We1[1 * H + j], v);
            v = fmaf(a2, We1[2 * H + j], v);
            v = fmaf(a3, We1[3 * H + j], v);
            ec[i][256 + j] = fmaxf(v, 0.f);
        }
    }
    __syncthreads();

    int q = j0 >> 2;  // float4 column offset
    float4 acc4[4];

    // Phase C: ef = t @ We2 + be2 (k<128), regs then back to ec[i][256:384]
    {
        const float4* W4 = (const float4*)We2;   // 32 float4 per row
        const float4* b4 = (const float4*)be2;
#pragma unroll
        for (int u = 0; u < 4; ++u) acc4[u] = b4[q + u];
        for (int k = 0; k < 128; ++k) {
            float a = ec[i][256 + k];
#pragma unroll
            for (int u = 0; u < 4; ++u) fma4(acc4[u], a, W4[k * 32 + q + u]);
        }
    }
    __syncthreads();
    {
        float4* dst = (float4*)&ec[i][256 + j0];
#pragma unroll
        for (int u = 0; u < 4; ++u) dst[u] = acc4[u];
    }
    __syncthreads();

    // Phase D: z1 = relu(ec @ Wc1 + bc1), k<384
    {
        const float4* W4 = (const float4*)Wc1;   // 32 float4 per row
        const float4* b4 = (const float4*)bc1;
#pragma unroll
        for (int u = 0; u < 4; ++u) acc4[u] = b4[q + u];
        for (int k = 0; k < 384; ++k) {
            float a = ec[i][k];
#pragma unroll
            for (int u = 0; u < 4; ++u) fma4(acc4[u], a, W4[k * 32 + q + u]);
        }
    }
    __syncthreads();
    {
        float4* dst = (float4*)&ec[i][j0];
#pragma unroll
        for (int u = 0; u < 4; ++u) {
            float4 r = acc4[u];
            r.x = fmaxf(r.x, 0.f); r.y = fmaxf(r.y, 0.f);
            r.z = fmaxf(r.z, 0.f); r.w = fmaxf(r.w, 0.f);
            dst[u] = r;
        }
    }
    __syncthreads();

    // Phase E: z2 = relu(z1 @ Wc2 + bc2), 64 outputs, k<128
    {
        int j1 = (tid & 7) * 8;
        int q2 = j1 >> 2;
        const float4* W4 = (const float4*)Wc2;   // 16 float4 per row
        const float4* b4 = (const float4*)bc2;
        float4 a2[2];
        a2[0] = b4[q2]; a2[1] = b4[q2 + 1];
        for (int k = 0; k < 128; ++k) {
            float a = ec[i][k];
            fma4(a2[0], a, W4[k * 16 + q2]);
            fma4(a2[1], a, W4[k * 16 + q2 + 1]);
        }
        __syncthreads();
        float4* dst = (float4*)&ec[i][128 + j1];
#pragma unroll
        for (int u = 0; u < 2; ++u) {
            float4 r = a2[u];
            r.x = fmaxf(r.x, 0.f); r.y = fmaxf(r.y, 0.f);
            r.z = fmaxf(r.z, 0.f); r.w = fmaxf(r.w, 0.f);
            dst[u] = r;
        }
    }
    __syncthreads();

    // Phase F: logits + log_softmax
    if (tid < TE) {
        int e = e0 + tid;
        if (e < E) {
            float l0 = bc3[0], l1 = bc3[1];
            for (int k = 0; k < 64; ++k) {
                float z = ec[tid][128 + k];
                l0 = fmaf(z, Wc3[k * 2 + 0], l0);
                l1 = fmaf(z, Wc3[k * 2 + 1], l1);
            }
            float m = fmaxf(l0, l1);
            float lse = m + logf(expf(l0 - m) + expf(l1 - m));
            out[(size_t)e * 2 + 0] = l0 - lse;
            out[(size_t)e * 2 + 1] = l1 - lse;
        }
    }
}

// ---------------- launch ----------------

extern "C" void kernel_launch(void* const* d_in, const int* in_sizes, int n_in,
                              void* d_out, int out_size, void* d_ws, size_t ws_size,
                              hipStream_t stream) {
    const float* x   = (const float*)d_in[0];
    const int*   ei  = (const int*)d_in[1];
    const float* ea  = (const float*)d_in[2];
    const float* W1  = (const float*)d_in[3];
    const float* b1  = (const float*)d_in[4];
    const float* W2  = (const float*)d_in[5];
    const float* b2  = (const float*)d_in[6];
    const float* W3  = (const float*)d_in[7];
    const float* b3  = (const float*)d_in[8];
    const float* We1 = (const float*)d_in[9];
    const float* be1 = (const float*)d_in[10];
    const float* We2 = (const float*)d_in[11];
    const float* be2 = (const float*)d_in[12];
    const float* Wc1 = (const float*)d_in[13];
    const float* bc1 = (const float*)d_in[14];
    const float* Wc2 = (const float*)d_in[15];
    const float* bc2 = (const float*)d_in[16];
    const float* Wc3 = (const float*)d_in[17];
    const float* bc3 = (const float*)d_in[18];
    float* out = (float*)d_out;

    int N = in_sizes[0] / 8;   // FN = 8
    int E = in_sizes[1] / 2;
    const int* row = ei;
    const int* col = ei + E;

    char* w = (char*)d_ws;
    int* cnt       = (int*)w;   w += (size_t)N * 4;
    int* col_start = (int*)w;   w += (size_t)(N + 4) * 4;
    int* cursor    = (int*)w;   w += (size_t)N * 4;
    int* csc_src   = (int*)w;   w += (size_t)E * 4;
    float* dinv    = (float*)w; w += (size_t)N * 4;
    float* h_a     = (float*)w; w += (size_t)N * H * 4;
    float* h_b     = (float*)w; w += (size_t)N * H * 4;
    float* hw      = (float*)w; w += (size_t)N * H * 4;

    hipMemsetAsync(cnt, 0, (size_t)N * 4, stream);
    count_kernel<<<(E + 255) / 256, 256, 0, stream>>>(col, E, cnt);
    scan_kernel<<<1, 1024, 0, stream>>>(cnt, N, E, col_start, cursor, dinv);
    scatter_kernel<<<(E + 255) / 256, 256, 0, stream>>>(row, col, E, cursor, csc_src);

    // layer 1 (K=8)
    node_gemm_kernel<<<(N * H + 255) / 256, 256, 0, stream>>>(x, W1, N, 8, hw);
    aggregate_kernel<<<N, H, 0, stream>>>(hw, col_start, csc_src, dinv, b1, h_a, N);
    // layer 2
    node_gemm_kernel<<<(N * H + 255) / 256, 256, 0, stream>>>(h_a, W2, N, H, hw);
    aggregate_kernel<<<N, H, 0, stream>>>(hw, col_start, csc_src, dinv, b2, h_b, N);
    // layer 3
    node_gemm_kernel<<<(N * H + 255) / 256, 256, 0, stream>>>(h_b, W3, N, H, hw);
    aggregate_kernel<<<N, H, 0, stream>>>(hw, col_start, csc_src, dinv, b3, h_a, N);

    // fused edge encoder + classifier + log_softmax
    classifier_kernel<<<(E + TE - 1) / TE, 256, 0, stream>>>(
        h_a, row, col, ea, We1, be1, We2, be2,
        Wc1, bc1, Wc2, bc2, Wc3, bc3, out, E);
}

// Round 2
// 1480.214 us; speedup vs baseline: 8.6318x; 8.6318x over previous
//
#include <hip/hip_runtime.h>
#include <math.h>

#define H 128

typedef __attribute__((ext_vector_type(8))) short short8;
typedef __attribute__((ext_vector_type(4))) float f32x4;

__device__ inline unsigned short f2bf(float f) {
    unsigned int u = __float_as_uint(f);
    unsigned int r = (u + 0x7fffu + ((u >> 16) & 1u)) >> 16;
    return (unsigned short)r;
}

__device__ inline void fma4(float4& acc, float a, const float4 w) {
    acc.x = fmaf(a, w.x, acc.x);
    acc.y = fmaf(a, w.y, acc.y);
    acc.z = fmaf(a, w.z, acc.z);
    acc.w = fmaf(a, w.w, acc.w);
}

// ---------------- graph build ----------------

__global__ void count_kernel(const int* __restrict__ col, int E, int* __restrict__ cnt) {
    int e = blockIdx.x * blockDim.x + threadIdx.x;
    if (e < E) atomicAdd(&cnt[col[e]], 1);
}

__global__ void scan_kernel(const int* __restrict__ cnt, int N, int E,
                            int* __restrict__ col_start, int* __restrict__ cursor,
                            float* __restrict__ dinv) {
    __shared__ int buf[1024];
    int tid = threadIdx.x;
    int run = 0;
    for (int base = 0; base < N; base += 1024) {
        int i = base + tid;
        int v = (i < N) ? cnt[i] : 0;
        buf[tid] = v;
        __syncthreads();
        for (int off = 1; off < 1024; off <<= 1) {
            int t = buf[tid];
            if (tid >= off) t += buf[tid - off];
            __syncthreads();
            buf[tid] = t;
            __syncthreads();
        }
        int incl = buf[tid];
        int tot  = buf[1023];
        if (i < N) {
            int excl = run + incl - v;
            col_start[i] = excl;
            cursor[i]    = excl;
            dinv[i] = rsqrtf((float)(v + 1));  // +1 self-loop
        }
        run += tot;
        __syncthreads();
    }
    if (tid == 0) col_start[N] = E;
}

__global__ void scatter_kernel(const int* __restrict__ row, const int* __restrict__ col, int E,
                               int* __restrict__ cursor, int* __restrict__ csc_src) {
    int e = blockIdx.x * blockDim.x + threadIdx.x;
    if (e < E) {
        int c = col[e];
        int p = atomicAdd(&cursor[c], 1);
        csc_src[p] = row[e];
    }
}

// ---------------- node transform (h @ W) ----------------

__global__ void node_gemm_kernel(const float* __restrict__ hin, const float* __restrict__ W,
                                 int N, int K, float* __restrict__ out) {
    int t = blockIdx.x * blockDim.x + threadIdx.x;
    if (t >= N * H) return;
    int j = t & (H - 1);
    int i = t >> 7;
    const float* hr = hin + (size_t)i * K;
    float acc = 0.f;
    for (int k = 0; k < K; ++k) acc = fmaf(hr[k], W[k * H + j], acc);
    out[t] = acc;
}

// ---------------- GCN aggregation (gather over CSC) ----------------

__global__ void aggregate_kernel(const float* __restrict__ hw, const int* __restrict__ col_start,
                                 const int* __restrict__ csc_src, const float* __restrict__ dinv,
                                 const float* __restrict__ bias, float* __restrict__ out, int N) {
    int i = blockIdx.x;
    int j = threadIdx.x;
    int s0 = col_start[i], s1 = col_start[i + 1];
    float acc = 0.f;
    for (int p = s0; p < s1; ++p) {
        int s = csc_src[p];
        acc = fmaf(dinv[s], hw[(size_t)s * H + j], acc);
    }
    float di = dinv[i];
    float v = fmaf(di, acc, fmaf(di * di, hw[(size_t)i * H + j], bias[j]));
    out[(size_t)i * H + j] = fmaxf(v, 0.f);
}

// same but writes bf16 (last GCN layer output feeds the MFMA classifier)
__global__ void aggregate_bf16_kernel(const float* __restrict__ hw, const int* __restrict__ col_start,
                                      const int* __restrict__ csc_src, const float* __restrict__ dinv,
                                      const float* __restrict__ bias, unsigned short* __restrict__ out, int N) {
    int i = blockIdx.x;
    int j = threadIdx.x;
    int s0 = col_start[i], s1 = col_start[i + 1];
    float acc = 0.f;
    for (int p = s0; p < s1; ++p) {
        int s = csc_src[p];
        acc = fmaf(dinv[s], hw[(size_t)s * H + j], acc);
    }
    float di = dinv[i];
    float v = fmaf(di, acc, fmaf(di * di, hw[(size_t)i * H + j], bias[j]));
    out[(size_t)i * H + j] = f2bf(fmaxf(v, 0.f));
}

// ---------------- classifier prep (weights -> fused / packed bf16) ----------------

// Weff[k][c] = sum_j We2[k][j] * Wc1[256+j][c]   (folds edge-MLP layer2 into Wc1)
__global__ void weff_kernel(const float* __restrict__ We2, const float* __restrict__ Wc1,
                            float* __restrict__ Weff) {
    int idx = blockIdx.x * blockDim.x + threadIdx.x;  // 16384
    int k = idx >> 7, c = idx & 127;
    float acc = 0.f;
    for (int j = 0; j < 128; ++j)
        acc = fmaf(We2[k * 128 + j], Wc1[(256 + j) * 128 + c], acc);
    Weff[idx] = acc;
}

// bc1p[c] = bc1[c] + sum_j be2[j]*Wc1[256+j][c]
__global__ void bc1p_kernel(const float* __restrict__ bc1, const float* __restrict__ be2,
                            const float* __restrict__ Wc1, float* __restrict__ bc1p) {
    int c = threadIdx.x;
    float acc = bc1[c];
    for (int j = 0; j < 128; ++j)
        acc = fmaf(be2[j], Wc1[(256 + j) * 128 + c], acc);
    bc1p[c] = acc;
}

// pack B (384x128: rows 0..255 = Wc1, 256..383 = Weff) into 16x16x32 bf16 B-fragment layout:
// Bp1[s][nt][lane][j] = B[s*32 + (lane>>4)*8 + j][nt*16 + (lane&15)]
__global__ void pack1_kernel(const float* __restrict__ Wc1, const float* __restrict__ Weff,
                             unsigned short* __restrict__ Bp1) {
    int idx = blockIdx.x * blockDim.x + threadIdx.x;  // 12*8*64 = 6144
    int s = idx >> 9;
    int nt = (idx >> 6) & 7;
    int lane = idx & 63;
    int quad = lane >> 4, lm = lane & 15;
    int n = nt * 16 + lm;
    int k0 = s * 32 + quad * 8;
    unsigned int p[4];
    for (int g = 0; g < 4; ++g) {
        int r0 = k0 + 2 * g, r1 = r0 + 1;
        float v0 = (r0 < 256) ? Wc1[r0 * 128 + n] : Weff[(r0 - 256) * 128 + n];
        float v1 = (r1 < 256) ? Wc1[r1 * 128 + n] : Weff[(r1 - 256) * 128 + n];
        p[g] = (unsigned int)f2bf(v0) | ((unsigned int)f2bf(v1) << 16);
    }
    *(uint4*)&Bp1[(size_t)idx * 8] = make_uint4(p[0], p[1], p[2], p[3]);
}

// pack Wc2 (128x64) likewise: Bp2[s][nt][lane][j], s<4, nt<4
__global__ void pack2_kernel(const float* __restrict__ Wc2, unsigned short* __restrict__ Bp2) {
    int idx = blockIdx.x * blockDim.x + threadIdx.x;  // 4*4*64 = 1024
    int s = idx >> 8;
    int nt = (idx >> 6) & 3;
    int lane = idx & 63;
    int quad = lane >> 4, lm = lane & 15;
    int n = nt * 16 + lm;
    int k0 = s * 32 + quad * 8;
    unsigned int p[4];
    for (int g = 0; g < 4; ++g) {
        float v0 = Wc2[(k0 + 2 * g) * 64 + n];
        float v1 = Wc2[(k0 + 2 * g + 1) * 64 + n];
        p[g] = (unsigned int)f2bf(v0) | ((unsigned int)f2bf(v1) << 16);
    }
    *(uint4*)&Bp2[(size_t)idx * 8] = make_uint4(p[0], p[1], p[2], p[3]);
}

// ---------------- fused MFMA classifier ----------------
// per block: 64 edges. A = [h[row] | h[col] | t] (384 bf16), z1 = relu(A@Bp1+bc1p),
// z2 = relu(z1@Bp2+bc2), logits = z2@Wc3+bc3, log_softmax.

__global__ __launch_bounds__(256, 3) void classifier_mfma(
    const unsigned short* __restrict__ hbf, const int* __restrict__ row, const int* __restrict__ col,
    const float* __restrict__ ea,
    const float* __restrict__ We1, const float* __restrict__ be1,
    const unsigned short* __restrict__ Bp1, const float* __restrict__ bc1p,
    const unsigned short* __restrict__ Bp2, const float* __restrict__ bc2,
    const float* __restrict__ Wc3, const float* __restrict__ bc3,
    float* __restrict__ out, int E) {
    __shared__ __align__(16) unsigned char smem[50688];
    unsigned short* At = (unsigned short*)smem;      // [64][392] bf16
    int* rS = (int*)(smem + 50176);
    int* cS = rS + 64;

    int tid = threadIdx.x;
    int e0 = blockIdx.x * 64;

    if (tid < 64) {
        int e = e0 + tid; if (e >= E) e = E - 1;
        rS[tid] = row[e]; cS[tid] = col[e];
    }
    __syncthreads();

    // gather h[row] -> At[:,0:128], h[col] -> At[:,128:256] (bf16 rows, 256 B each)
    {
        const uint4* src4 = (const uint4*)hbf;  // 16 uint4 per node row
        for (int u = tid; u < 2048; u += 256) {
            int half = u >> 10;
            int i = (u >> 4) & 63;
            int l16 = u & 15;
            int node = half ? cS[i] : rS[i];
            uint4 v = src4[(size_t)node * 16 + l16];
            *(uint4*)&At[i * 392 + half * 128 + l16 * 8] = v;
        }
    }
    // t = relu(ea@We1+be1) -> At[:,256:384]
    {
        int i = tid >> 2, jv0 = (tid & 3) * 32;
        int e = e0 + i; if (e >= E) e = E - 1;
        float4 a = ((const float4*)ea)[e];
        const float4* W14 = (const float4*)We1;
        const float4* b14 = (const float4*)be1;
        for (int g = 0; g < 4; ++g) {
            int j0 = jv0 + g * 8, q = j0 >> 2;
            float4 r0 = b14[q], r1 = b14[q + 1];
            fma4(r0, a.x, W14[q]);        fma4(r1, a.x, W14[q + 1]);
            fma4(r0, a.y, W14[32 + q]);   fma4(r1, a.y, W14[32 + q + 1]);
            fma4(r0, a.z, W14[64 + q]);   fma4(r1, a.z, W14[64 + q + 1]);
            fma4(r0, a.w, W14[96 + q]);   fma4(r1, a.w, W14[96 + q + 1]);
            unsigned int p0 = (unsigned int)f2bf(fmaxf(r0.x, 0.f)) | ((unsigned int)f2bf(fmaxf(r0.y, 0.f)) << 16);
            unsigned int p1 = (unsigned int)f2bf(fmaxf(r0.z, 0.f)) | ((unsigned int)f2bf(fmaxf(r0.w, 0.f)) << 16);
            unsigned int p2 = (unsigned int)f2bf(fmaxf(r1.x, 0.f)) | ((unsigned int)f2bf(fmaxf(r1.y, 0.f)) << 16);
            unsigned int p3 = (unsigned int)f2bf(fmaxf(r1.z, 0.f)) | ((unsigned int)f2bf(fmaxf(r1.w, 0.f)) << 16);
            *(uint4*)&At[i * 392 + 256 + j0] = make_uint4(p0, p1, p2, p3);
        }
    }
    __syncthreads();

    int lane = tid & 63, w = tid >> 6;
    int lm = lane & 15, quad = lane >> 4;

    // GEMM1: z1[64][128] = relu(A @ B + bc1p). wave w owns n-tiles 2w, 2w+1; B frags loaded once.
    f32x4 acc0[4], acc1[4];
    {
        float bv0 = bc1p[2 * w * 16 + lm];
        float bv1 = bc1p[(2 * w + 1) * 16 + lm];
        for (int m = 0; m < 4; ++m)
            for (int r = 0; r < 4; ++r) { acc0[m][r] = bv0; acc1[m][r] = bv1; }
    }
#pragma unroll
    for (int s = 0; s < 12; ++s) {
        short8 b0 = *(const short8*)&Bp1[((size_t)(s * 8 + 2 * w) * 64 + lane) * 8];
        short8 b1 = *(const short8*)&Bp1[((size_t)(s * 8 + 2 * w + 1) * 64 + lane) * 8];
#pragma unroll
        for (int m = 0; m < 4; ++m) {
            short8 afr = *(const short8*)&At[(m * 16 + lm) * 392 + s * 32 + quad * 8];
            acc0[m] = __builtin_amdgcn_mfma_f32_16x16x32_bf16(afr, b0, acc0[m], 0, 0, 0);
            acc1[m] = __builtin_amdgcn_mfma_f32_16x16x32_bf16(afr, b1, acc1[m], 0, 0, 0);
        }
    }
    __syncthreads();

    // relu + store z1 as bf16 rows (A-layout) into smem[0:17408)
    unsigned short* z1 = (unsigned short*)smem;  // [64][136]
    for (int m = 0; m < 4; ++m)
        for (int r = 0; r < 4; ++r) {
            int rw = m * 16 + quad * 4 + r;
            z1[rw * 136 + 2 * w * 16 + lm]       = f2bf(fmaxf(acc0[m][r], 0.f));
            z1[rw * 136 + (2 * w + 1) * 16 + lm] = f2bf(fmaxf(acc1[m][r], 0.f));
        }
    __syncthreads();

    // GEMM2: z2[64][64] = relu(z1 @ Wc2 + bc2). wave w owns n-tile w.
    float* z2 = (float*)(smem + 17408);  // [64][69] fp32
    {
        f32x4 acc2[4];
        float bv = bc2[w * 16 + lm];
        for (int m = 0; m < 4; ++m)
            for (int r = 0; r < 4; ++r) acc2[m][r] = bv;
#pragma unroll
        for (int s = 0; s < 4; ++s) {
            short8 b = *(const short8*)&Bp2[((size_t)(s * 4 + w) * 64 + lane) * 8];
#pragma unroll
            for (int m = 0; m < 4; ++m) {
                short8 afr = *(const short8*)&z1[(m * 16 + lm) * 136 + s * 32 + quad * 8];
                acc2[m] = __builtin_amdgcn_mfma_f32_16x16x32_bf16(afr, b, acc2[m], 0, 0, 0);
            }
        }
        for (int m = 0; m < 4; ++m)
            for (int r = 0; r < 4; ++r)
                z2[(m * 16 + quad * 4 + r) * 69 + w * 16 + lm] = fmaxf(acc2[m][r], 0.f);
    }
    __syncthreads();

    // logits + log_softmax
    if (tid < 64) {
        int e = e0 + tid;
        if (e < E) {
            const float* zr = z2 + tid * 69;
            float l0 = bc3[0], l1 = bc3[1];
            for (int k = 0; k < 64; ++k) {
                float z = zr[k];
                l0 = fmaf(z, Wc3[2 * k], l0);
                l1 = fmaf(z, Wc3[2 * k + 1], l1);
            }
            float m = fmaxf(l0, l1);
            float lse = m + logf(expf(l0 - m) + expf(l1 - m));
            ((float2*)out)[e] = make_float2(l0 - lse, l1 - lse);
        }
    }
}

// ---------------- launch ----------------

extern "C" void kernel_launch(void* const* d_in, const int* in_sizes, int n_in,
                              void* d_out, int out_size, void* d_ws, size_t ws_size,
                              hipStream_t stream) {
    const float* x   = (const float*)d_in[0];
    const int*   ei  = (const int*)d_in[1];
    const float* ea  = (const float*)d_in[2];
    const float* W1  = (const float*)d_in[3];
    const float* b1  = (const float*)d_in[4];
    const float* W2  = (const float*)d_in[5];
    const float* b2  = (const float*)d_in[6];
    const float* W3  = (const float*)d_in[7];
    const float* b3  = (const float*)d_in[8];
    const float* We1 = (const float*)d_in[9];
    const float* be1 = (const float*)d_in[10];
    const float* We2 = (const float*)d_in[11];
    const float* be2 = (const float*)d_in[12];
    const float* Wc1 = (const float*)d_in[13];
    const float* bc1 = (const float*)d_in[14];
    const float* Wc2 = (const float*)d_in[15];
    const float* bc2 = (const float*)d_in[16];
    const float* Wc3 = (const float*)d_in[17];
    const float* bc3 = (const float*)d_in[18];
    float* out = (float*)d_out;

    int N = in_sizes[0] / 8;   // FN = 8
    int E = in_sizes[1] / 2;
    const int* row = ei;
    const int* col = ei + E;

    char* w = (char*)d_ws;
    int* cnt       = (int*)w;   w += (size_t)N * 4;
    int* col_start = (int*)w;   w += (size_t)(N + 4) * 4;
    int* cursor    = (int*)w;   w += (size_t)N * 4;
    int* csc_src   = (int*)w;   w += (size_t)E * 4;
    float* dinv    = (float*)w; w += (size_t)N * 4;
    float* h_a     = (float*)w; w += (size_t)N * H * 4;
    float* h_b     = (float*)w; w += (size_t)N * H * 4;
    float* hw_     = (float*)w; w += (size_t)N * H * 4;
    float* Weff    = (float*)w; w += 128 * 128 * 4;
    float* bc1p    = (float*)w; w += 512;
    unsigned short* Bp1 = (unsigned short*)w; w += 12 * 8 * 64 * 8 * 2;
    unsigned short* Bp2 = (unsigned short*)w; w += 4 * 4 * 64 * 8 * 2;
    unsigned short* hbf = (unsigned short*)h_a;  // h_a is free by the time layer-3 aggregate runs

    hipMemsetAsync(cnt, 0, (size_t)N * 4, stream);
    count_kernel<<<(E + 255) / 256, 256, 0, stream>>>(col, E, cnt);
    scan_kernel<<<1, 1024, 0, stream>>>(cnt, N, E, col_start, cursor, dinv);
    scatter_kernel<<<(E + 255) / 256, 256, 0, stream>>>(row, col, E, cursor, csc_src);

    // classifier weight prep (tiny)
    weff_kernel<<<64, 256, 0, stream>>>(We2, Wc1, Weff);
    bc1p_kernel<<<1, 128, 0, stream>>>(bc1, be2, Wc1, bc1p);
    pack1_kernel<<<24, 256, 0, stream>>>(Wc1, Weff, Bp1);
    pack2_kernel<<<4, 256, 0, stream>>>(Wc2, Bp2);

    // layer 1 (K=8)
    node_gemm_kernel<<<(N * H + 255) / 256, 256, 0, stream>>>(x, W1, N, 8, hw_);
    aggregate_kernel<<<N, H, 0, stream>>>(hw_, col_start, csc_src, dinv, b1, h_a, N);
    // layer 2
    node_gemm_kernel<<<(N * H + 255) / 256, 256, 0, stream>>>(h_a, W2, N, H, hw_);
    aggregate_kernel<<<N, H, 0, stream>>>(hw_, col_start, csc_src, dinv, b2, h_b, N);
    // layer 3 -> bf16 node features
    node_gemm_kernel<<<(N * H + 255) / 256, 256, 0, stream>>>(h_b, W3, N, H, hw_);
    aggregate_bf16_kernel<<<N, H, 0, stream>>>(hw_, col_start, csc_src, dinv, b3, hbf, N);

    // fused MFMA classifier
    classifier_mfma<<<(E + 63) / 64, 256, 0, stream>>>(
        hbf, row, col, ea, We1, be1, Bp1, bc1p, Bp2, bc2, Wc3, bc3, out, E);
}

// Round 3
// 890.197 us; speedup vs baseline: 14.3529x; 1.6628x over previous
//
#include <hip/hip_runtime.h>
#include <math.h>

#define H 128
#define STC 152   // LDS stride (shorts) for bf16 A-tiles: 304 B, 16B-aligned, 2-way banks
#define SPQS 132  // LDS stride (floats) for Spq

typedef __attribute__((ext_vector_type(8))) short short8;
typedef __attribute__((ext_vector_type(4))) float f32x4;

__device__ inline unsigned short f2bf(float f) {
    unsigned int u = __float_as_uint(f);
    return (unsigned short)((u + 0x7fffu + ((u >> 16) & 1u)) >> 16);
}

__device__ inline void fma4(float4& acc, float a, const float4 w) {
    acc.x = fmaf(a, w.x, acc.x);
    acc.y = fmaf(a, w.y, acc.y);
    acc.z = fmaf(a, w.z, acc.z);
    acc.w = fmaf(a, w.w, acc.w);
}

// ---------------- graph build ----------------

__global__ void count_kernel(const int* __restrict__ col, int E, int* __restrict__ cnt) {
    int e = blockIdx.x * blockDim.x + threadIdx.x;
    if (e < E) atomicAdd(&cnt[col[e]], 1);
}

// block sums over 1024-element chunks
__global__ void scan_sum_kernel(const int* __restrict__ cnt, int N, int* __restrict__ bsum) {
    int b = blockIdx.x, t = threadIdx.x;
    int base = b * 1024 + t * 4;
    int s = 0;
#pragma unroll
    for (int g = 0; g < 4; ++g) {
        int i = base + g;
        if (i < N) s += cnt[i];
    }
    for (int off = 32; off >= 1; off >>= 1) s += __shfl_down(s, off, 64);
    __shared__ int ws[4];
    if ((t & 63) == 0) ws[t >> 6] = s;
    __syncthreads();
    if (t == 0) bsum[b] = ws[0] + ws[1] + ws[2] + ws[3];
}

__global__ void scan_offsets_kernel(const int* __restrict__ bsum, int nb,
                                    int* __restrict__ boff, int* __restrict__ col_start, int N) {
    int lane = threadIdx.x;
    int v = (lane < nb) ? bsum[lane] : 0;
    int incl = v;
    for (int off = 1; off < 64; off <<= 1) {
        int u = __shfl_up(incl, off, 64);
        if (lane >= off) incl += u;
    }
    if (lane < nb) boff[lane] = incl - v;
    if (lane == 63) col_start[N] = incl;
}

__global__ void scan_write_kernel(const int* __restrict__ cnt, int N, const int* __restrict__ boff,
                                  int* __restrict__ col_start, int* __restrict__ cursor,
                                  float* __restrict__ dinv) {
    int b = blockIdx.x, t = threadIdx.x;
    int lane = t & 63, wv = t >> 6;
    int base = b * 1024 + t * 4;
    int c[4];
    int s = 0;
#pragma unroll
    for (int g = 0; g < 4; ++g) {
        int i = base + g;
        c[g] = (i < N) ? cnt[i] : 0;
        s += c[g];
    }
    int incl = s;
    for (int off = 1; off < 64; off <<= 1) {
        int u = __shfl_up(incl, off, 64);
        if (lane >= off) incl += u;
    }
    __shared__ int ws[4];
    if (lane == 63) ws[wv] = incl;
    __syncthreads();
    int run = boff[b] + incl - s;
    for (int w = 0; w < wv; ++w) run += ws[w];
#pragma unroll
    for (int g = 0; g < 4; ++g) {
        int i = base + g;
        if (i < N) {
            col_start[i] = run;
            cursor[i] = run;
            dinv[i] = rsqrtf((float)(c[g] + 1));
            run += c[g];
        }
    }
}

__global__ void scatter_kernel(const int* __restrict__ row, const int* __restrict__ col, int E,
                               int* __restrict__ cursor, int* __restrict__ csc_src) {
    int e = blockIdx.x * blockDim.x + threadIdx.x;
    if (e < E) {
        int c = col[e];
        int p = atomicAdd(&cursor[c], 1);
        csc_src[p] = row[e];
    }
}

// ---------------- GCN: aggregate-then-transform ----------------

// layer-1 aggregation on raw x (8 features)
__global__ void aggx_kernel(const float* __restrict__ x, const int* __restrict__ col_start,
                            const int* __restrict__ csc_src, const float* __restrict__ dinv,
                            float* __restrict__ aggx, int N) {
    int t = blockIdx.x * blockDim.x + threadIdx.x;
    int i = t >> 3, f = t & 7;
    if (i >= N) return;
    int s0 = col_start[i], s1 = col_start[i + 1];
    float acc = 0.f;
    for (int p = s0; p < s1; ++p) {
        int s = csc_src[p];
        acc = fmaf(dinv[s], x[s * 8 + f], acc);
    }
    float di = dinv[i];
    aggx[i * 8 + f] = fmaf(di, acc, di * di * x[i * 8 + f]);
}

__global__ void xform8_kernel(const float* __restrict__ aggx, const float* __restrict__ W,
                              const float* __restrict__ b, float* __restrict__ out, int N) {
    int t = blockIdx.x * 256 + threadIdx.x;
    int i = t >> 7, j = t & 127;
    if (i >= N) return;
    const float* ar = aggx + i * 8;
    float acc = b[j];
#pragma unroll
    for (int k = 0; k < 8; ++k) acc = fmaf(ar[k], W[k * 128 + j], acc);
    out[(size_t)i * 128 + j] = fmaxf(acc, 0.f);
}

// wave-per-node aggregation, float2/lane, 4-way MLP on the gather chain
__global__ __launch_bounds__(256) void agg128_kernel(
    const float* __restrict__ h, const int* __restrict__ col_start,
    const int* __restrict__ csc_src, const float* __restrict__ dinv,
    float* __restrict__ out, int N) {
    int wv = threadIdx.x >> 6, lane = threadIdx.x & 63;
    int i = blockIdx.x * 4 + wv;
    if (i >= N) return;
    const float2* h2 = (const float2*)h;
    int s0 = col_start[i], s1 = col_start[i + 1];
    float ax = 0.f, ay = 0.f;
    int p = s0;
    for (; p + 4 <= s1; p += 4) {
        int sa = csc_src[p], sb = csc_src[p + 1], sc = csc_src[p + 2], sd = csc_src[p + 3];
        float da = dinv[sa], db = dinv[sb], dc = dinv[sc], dd = dinv[sd];
        float2 va = h2[(size_t)sa * 64 + lane];
        float2 vb = h2[(size_t)sb * 64 + lane];
        float2 vc = h2[(size_t)sc * 64 + lane];
        float2 vd = h2[(size_t)sd * 64 + lane];
        ax = fmaf(da, va.x, ax); ay = fmaf(da, va.y, ay);
        ax = fmaf(db, vb.x, ax); ay = fmaf(db, vb.y, ay);
        ax = fmaf(dc, vc.x, ax); ay = fmaf(dc, vc.y, ay);
        ax = fmaf(dd, vd.x, ax); ay = fmaf(dd, vd.y, ay);
    }
    for (; p < s1; ++p) {
        int s = csc_src[p];
        float d = dinv[s];
        float2 v = h2[(size_t)s * 64 + lane];
        ax = fmaf(d, v.x, ax); ay = fmaf(d, v.y, ay);
    }
    float di = dinv[i];
    float2 self = h2[(size_t)i * 64 + lane];
    float2 r;
    r.x = fmaf(di, ax, di * di * self.x);
    r.y = fmaf(di, ay, di * di * self.y);
    ((float2*)out)[(size_t)i * 64 + lane] = r;
}

// transform: out = relu(agg @ W + b), 8 rows/block, LDS-staged rows, float4 W stream
__global__ __launch_bounds__(256) void xform128_kernel(
    const float* __restrict__ agg, const float* __restrict__ W, const float* __restrict__ b,
    float* __restrict__ out, int N) {
    __shared__ float rows8[8][128];
    int i0 = blockIdx.x * 8, t = threadIdx.x;
    int r = t >> 5, c = t & 31;
    {
        int i = i0 + r;
        float4 v = (i < N) ? ((const float4*)agg)[(size_t)i * 32 + c] : make_float4(0, 0, 0, 0);
        *(float4*)&rows8[r][c * 4] = v;
    }
    __syncthreads();
    int i = i0 + r;
    if (i >= N) return;
    const float4* W4 = (const float4*)W;
    float4 acc = ((const float4*)b)[c];
#pragma unroll 4
    for (int k = 0; k < 128; ++k) fma4(acc, rows8[r][k], W4[k * 32 + c]);
    acc.x = fmaxf(acc.x, 0.f); acc.y = fmaxf(acc.y, 0.f);
    acc.z = fmaxf(acc.z, 0.f); acc.w = fmaxf(acc.w, 0.f);
    ((float4*)out)[(size_t)i * 32 + c] = acc;
}

__global__ __launch_bounds__(256) void xform128bf_kernel(
    const float* __restrict__ agg, const float* __restrict__ W, const float* __restrict__ b,
    unsigned short* __restrict__ out, int N) {
    __shared__ float rows8[8][128];
    int i0 = blockIdx.x * 8, t = threadIdx.x;
    int r = t >> 5, c = t & 31;
    {
        int i = i0 + r;
        float4 v = (i < N) ? ((const float4*)agg)[(size_t)i * 32 + c] : make_float4(0, 0, 0, 0);
        *(float4*)&rows8[r][c * 4] = v;
    }
    __syncthreads();
    int i = i0 + r;
    if (i >= N) return;
    const float4* W4 = (const float4*)W;
    float4 acc = ((const float4*)b)[c];
#pragma unroll 4
    for (int k = 0; k < 128; ++k) fma4(acc, rows8[r][k], W4[k * 32 + c]);
    unsigned int p0 = (unsigned int)f2bf(fmaxf(acc.x, 0.f)) | ((unsigned int)f2bf(fmaxf(acc.y, 0.f)) << 16);
    unsigned int p1 = (unsigned int)f2bf(fmaxf(acc.z, 0.f)) | ((unsigned int)f2bf(fmaxf(acc.w, 0.f)) << 16);
    *(uint2*)&out[(size_t)i * 128 + c * 4] = make_uint2(p0, p1);
}

// ---------------- classifier weight prep ----------------

__global__ void weff_kernel(const float* __restrict__ We2, const float* __restrict__ Wc1,
                            float* __restrict__ Weff) {
    int idx = blockIdx.x * blockDim.x + threadIdx.x;  // 16384
    int k = idx >> 7, c = idx & 127;
    float acc = 0.f;
    for (int j = 0; j < 128; ++j)
        acc = fmaf(We2[k * 128 + j], Wc1[(256 + j) * 128 + c], acc);
    Weff[idx] = acc;
}

__global__ void bc1p_kernel(const float* __restrict__ bc1, const float* __restrict__ be2,
                            const float* __restrict__ Wc1, float* __restrict__ bc1p) {
    int c = threadIdx.x;
    float acc = bc1[c];
    for (int j = 0; j < 128; ++j)
        acc = fmaf(be2[j], Wc1[(256 + j) * 128 + c], acc);
    bc1p[c] = acc;
}

// pack 128x128 fp32 -> bf16 16x16x32 B-fragments: dst[s<4][nt<8][lane][8]
__global__ void packg_kernel(const float* __restrict__ src, unsigned short* __restrict__ dst) {
    int idx = blockIdx.x * 256 + threadIdx.x;  // 2048
    int s = idx >> 9, nt = (idx >> 6) & 7, lane = idx & 63;
    int quad = lane >> 4, lm = lane & 15;
    int n = nt * 16 + lm, k0 = s * 32 + quad * 8;
    unsigned int p[4];
#pragma unroll
    for (int g = 0; g < 4; ++g) {
        p[g] = (unsigned int)f2bf(src[(k0 + 2 * g) * 128 + n]) |
               ((unsigned int)f2bf(src[(k0 + 2 * g + 1) * 128 + n]) << 16);
    }
    *(uint4*)&dst[(size_t)idx * 8] = make_uint4(p[0], p[1], p[2], p[3]);
}

// pack Wc2 (128x64): dst[s<4][nt<4][lane][8]
__global__ void pack2_kernel(const float* __restrict__ Wc2, unsigned short* __restrict__ Bp2) {
    int idx = blockIdx.x * 256 + threadIdx.x;  // 1024
    int s = idx >> 8, nt = (idx >> 6) & 3, lane = idx & 63;
    int quad = lane >> 4, lm = lane & 15;
    int n = nt * 16 + lm, k0 = s * 32 + quad * 8;
    unsigned int p[4];
#pragma unroll
    for (int g = 0; g < 4; ++g) {
        p[g] = (unsigned int)f2bf(Wc2[(k0 + 2 * g) * 64 + n]) |
               ((unsigned int)f2bf(Wc2[(k0 + 2 * g + 1) * 64 + n]) << 16);
    }
    *(uint4*)&Bp2[(size_t)idx * 8] = make_uint4(p[0], p[1], p[2], p[3]);
}

// ---------------- P/Q precompute: P = h3@Wc1a + bc1p, Q = h3@Wc1b (bf16 MFMA) ----------------

__global__ __launch_bounds__(256) void pq_kernel(
    const unsigned short* __restrict__ hbf,
    const unsigned short* __restrict__ BpA, const unsigned short* __restrict__ BpB,
    const float* __restrict__ bc1p, float* __restrict__ P, float* __restrict__ Q, int N) {
    __shared__ __align__(16) unsigned short At[64 * STC];
    int tid = threadIdx.x;
    int i0 = blockIdx.x * 64;
    for (int u = tid; u < 1024; u += 256) {
        int i = u >> 4, l16 = u & 15;
        int node = i0 + i; if (node >= N) node = N - 1;
        uint4 v = ((const uint4*)hbf)[(size_t)node * 16 + l16];
        *(uint4*)&At[i * STC + l16 * 8] = v;
    }
    __syncthreads();
    int lane = tid & 63, w = tid >> 6, lm = lane & 15, quad = lane >> 4;
    int half = w & 1;
    const unsigned short* Bp = (w >> 1) ? BpB : BpA;
    float* O = (w >> 1) ? Q : P;
    f32x4 acc[4][4];  // [nt][m]
    for (int nt = 0; nt < 4; ++nt) {
        float bv = (w >> 1) ? 0.f : bc1p[half * 64 + nt * 16 + lm];
        for (int m = 0; m < 4; ++m)
            for (int r = 0; r < 4; ++r) acc[nt][m][r] = bv;
    }
#pragma unroll
    for (int s = 0; s < 4; ++s) {
        short8 afr[4];
#pragma unroll
        for (int m = 0; m < 4; ++m)
            afr[m] = *(const short8*)&At[(m * 16 + lm) * STC + s * 32 + quad * 8];
#pragma unroll
        for (int nt = 0; nt < 4; ++nt) {
            short8 bfr = *(const short8*)&Bp[((size_t)(s * 8 + half * 4 + nt) * 64 + lane) * 8];
#pragma unroll
            for (int m = 0; m < 4; ++m)
                acc[nt][m] = __builtin_amdgcn_mfma_f32_16x16x32_bf16(afr[m], bfr, acc[nt][m], 0, 0, 0);
        }
    }
    for (int nt = 0; nt < 4; ++nt)
        for (int m = 0; m < 4; ++m)
            for (int r = 0; r < 4; ++r) {
                int rw = i0 + m * 16 + quad * 4 + r;
                if (rw < N) O[(size_t)rw * 128 + half * 64 + nt * 16 + lm] = acc[nt][m][r];
            }
}

// ---------------- fused classifier: z1 = relu(P[row]+Q[col]+t@Weff), z2, logits ----------------

__global__ __launch_bounds__(256, 3) void classifier_mfma(
    const int* __restrict__ row, const int* __restrict__ col, const float* __restrict__ ea,
    const float* __restrict__ We1, const float* __restrict__ be1,
    const float* __restrict__ P, const float* __restrict__ Q,
    const unsigned short* __restrict__ BpU, const unsigned short* __restrict__ Bp2,
    const float* __restrict__ bc2, const float* __restrict__ Wc3, const float* __restrict__ bc3,
    float* __restrict__ out, int E) {
    __shared__ __align__(16) unsigned char smem[53760];
    float* Spq = (float*)smem;                            // [64][132] fp32
    unsigned short* z1 = (unsigned short*)smem;           // [64][152] bf16 (reuse)
    unsigned short* At = (unsigned short*)(smem + 33792); // [64][152] bf16
    float* z2 = (float*)(smem + 33792);                   // [64][69] fp32 (reuse)
    int* rS = (int*)(smem + 53248);
    int* cS = rS + 64;

    int tid = threadIdx.x;
    int e0 = blockIdx.x * 64;

    if (tid < 64) {
        int e = e0 + tid; if (e >= E) e = E - 1;
        rS[tid] = row[e]; cS[tid] = col[e];
    }
    __syncthreads();

    // stage Spq = P[row] + Q[col]  (bias already folded into P)
    {
        const float4* P4 = (const float4*)P;
        const float4* Q4 = (const float4*)Q;
        for (int u = tid; u < 2048; u += 256) {
            int i = u >> 5, c = u & 31;
            float4 p = P4[(size_t)rS[i] * 32 + c];
            float4 q = Q4[(size_t)cS[i] * 32 + c];
            p.x += q.x; p.y += q.y; p.z += q.z; p.w += q.w;
            *(float4*)&Spq[i * SPQS + c * 4] = p;
        }
    }
    // stage t = relu(ea@We1+be1) -> At (bf16)
    {
        int i = tid >> 2, jv0 = (tid & 3) * 32;
        int e = e0 + i; if (e >= E) e = E - 1;
        float4 a = ((const float4*)ea)[e];
        const float4* W14 = (const float4*)We1;
        const float4* b14 = (const float4*)be1;
        for (int g = 0; g < 4; ++g) {
            int j0 = jv0 + g * 8, q = j0 >> 2;
            float4 r0 = b14[q], r1 = b14[q + 1];
            fma4(r0, a.x, W14[q]);      fma4(r1, a.x, W14[q + 1]);
            fma4(r0, a.y, W14[32 + q]); fma4(r1, a.y, W14[32 + q + 1]);
            fma4(r0, a.z, W14[64 + q]); fma4(r1, a.z, W14[64 + q + 1]);
            fma4(r0, a.w, W14[96 + q]); fma4(r1, a.w, W14[96 + q + 1]);
            unsigned int p0 = (unsigned int)f2bf(fmaxf(r0.x, 0.f)) | ((unsigned int)f2bf(fmaxf(r0.y, 0.f)) << 16);
            unsigned int p1 = (unsigned int)f2bf(fmaxf(r0.z, 0.f)) | ((unsigned int)f2bf(fmaxf(r0.w, 0.f)) << 16);
            unsigned int p2 = (unsigned int)f2bf(fmaxf(r1.x, 0.f)) | ((unsigned int)f2bf(fmaxf(r1.y, 0.f)) << 16);
            unsigned int p3 = (unsigned int)f2bf(fmaxf(r1.z, 0.f)) | ((unsigned int)f2bf(fmaxf(r1.w, 0.f)) << 16);
            *(uint4*)&At[i * STC + j0] = make_uint4(p0, p1, p2, p3);
        }
    }
    __syncthreads();

    int lane = tid & 63, w = tid >> 6, lm = lane & 15, quad = lane >> 4;

    // GEMM_t: U = t @ Weff (K=128); wave w owns n-tiles 2w, 2w+1
    f32x4 acc0[4], acc1[4];
    for (int m = 0; m < 4; ++m)
        for (int r = 0; r < 4; ++r) { acc0[m][r] = 0.f; acc1[m][r] = 0.f; }
#pragma unroll
    for (int s = 0; s < 4; ++s) {
        short8 b0 = *(const short8*)&BpU[((size_t)(s * 8 + 2 * w) * 64 + lane) * 8];
        short8 b1 = *(const short8*)&BpU[((size_t)(s * 8 + 2 * w + 1) * 64 + lane) * 8];
#pragma unroll
        for (int m = 0; m < 4; ++m) {
            short8 afr = *(const short8*)&At[(m * 16 + lm) * STC + s * 32 + quad * 8];
            acc0[m] = __builtin_amdgcn_mfma_f32_16x16x32_bf16(afr, b0, acc0[m], 0, 0, 0);
            acc1[m] = __builtin_amdgcn_mfma_f32_16x16x32_bf16(afr, b1, acc1[m], 0, 0, 0);
        }
    }
    // z1 = relu(U + Spq) in registers
    for (int m = 0; m < 4; ++m)
        for (int r = 0; r < 4; ++r) {
            int rw = m * 16 + quad * 4 + r;
            acc0[m][r] = fmaxf(acc0[m][r] + Spq[rw * SPQS + 32 * w + lm], 0.f);
            acc1[m][r] = fmaxf(acc1[m][r] + Spq[rw * SPQS + 32 * w + 16 + lm], 0.f);
        }
    __syncthreads();
    // write z1 bf16 (overwrites Spq region)
    for (int m = 0; m < 4; ++m)
        for (int r = 0; r < 4; ++r) {
            int rw = m * 16 + quad * 4 + r;
            z1[rw * STC + 32 * w + lm]      = f2bf(acc0[m][r]);
            z1[rw * STC + 32 * w + 16 + lm] = f2bf(acc1[m][r]);
        }
    __syncthreads();

    // GEMM2: z2 = relu(z1 @ Wc2 + bc2); wave w owns n-tile w
    {
        f32x4 acc2[4];
        float bv = bc2[w * 16 + lm];
        for (int m = 0; m < 4; ++m)
            for (int r = 0; r < 4; ++r) acc2[m][r] = bv;
#pragma unroll
        for (int s = 0; s < 4; ++s) {
            short8 b = *(const short8*)&Bp2[((size_t)(s * 4 + w) * 64 + lane) * 8];
#pragma unroll
            for (int m = 0; m < 4; ++m) {
                short8 afr = *(const short8*)&z1[(m * 16 + lm) * STC + s * 32 + quad * 8];
                acc2[m] = __builtin_amdgcn_mfma_f32_16x16x32_bf16(afr, b, acc2[m], 0, 0, 0);
            }
        }
        for (int m = 0; m < 4; ++m)
            for (int r = 0; r < 4; ++r)
                z2[(m * 16 + quad * 4 + r) * 69 + w * 16 + lm] = fmaxf(acc2[m][r], 0.f);
    }
    __syncthreads();

    // logits + log_softmax
    if (tid < 64) {
        int e = e0 + tid;
        if (e < E) {
            const float* zr = z2 + tid * 69;
            float l0 = bc3[0], l1 = bc3[1];
            for (int k = 0; k < 64; ++k) {
                float z = zr[k];
                l0 = fmaf(z, Wc3[2 * k], l0);
                l1 = fmaf(z, Wc3[2 * k + 1], l1);
            }
            float m = fmaxf(l0, l1);
            float lse = m + logf(expf(l0 - m) + expf(l1 - m));
            ((float2*)out)[e] = make_float2(l0 - lse, l1 - lse);
        }
    }
}

// ---------------- launch ----------------

extern "C" void kernel_launch(void* const* d_in, const int* in_sizes, int n_in,
                              void* d_out, int out_size, void* d_ws, size_t ws_size,
                              hipStream_t stream) {
    const float* x   = (const float*)d_in[0];
    const int*   ei  = (const int*)d_in[1];
    const float* ea  = (const float*)d_in[2];
    const float* W1  = (const float*)d_in[3];
    const float* b1  = (const float*)d_in[4];
    const float* W2  = (const float*)d_in[5];
    const float* b2  = (const float*)d_in[6];
    const float* W3  = (const float*)d_in[7];
    const float* b3  = (const float*)d_in[8];
    const float* We1 = (const float*)d_in[9];
    const float* be1 = (const float*)d_in[10];
    const float* We2 = (const float*)d_in[11];
    const float* be2 = (const float*)d_in[12];
    const float* Wc1 = (const float*)d_in[13];
    const float* bc1 = (const float*)d_in[14];
    const float* Wc2 = (const float*)d_in[15];
    const float* bc2 = (const float*)d_in[16];
    const float* Wc3 = (const float*)d_in[17];
    const float* bc3 = (const float*)d_in[18];
    float* out = (float*)d_out;

    int N = in_sizes[0] / 8;
    int E = in_sizes[1] / 2;
    const int* row = ei;
    const int* col = ei + E;
    int NB = (N + 1023) / 1024;

    char* w = (char*)d_ws;
    auto alloc = [&](size_t bytes) { void* p = (void*)w; w += (bytes + 255) & ~(size_t)255; return p; };
    int*   cnt       = (int*)alloc((size_t)N * 4);
    int*   col_start = (int*)alloc((size_t)(N + 1) * 4);
    int*   cursor    = (int*)alloc((size_t)N * 4);
    int*   csc_src   = (int*)alloc((size_t)E * 4);
    float* dinv      = (float*)alloc((size_t)N * 4);
    int*   bsum      = (int*)alloc(64 * 4);
    int*   boff      = (int*)alloc(64 * 4);
    float* Weff      = (float*)alloc(128 * 128 * 4);
    float* bc1p      = (float*)alloc(128 * 4);
    unsigned short* BpA = (unsigned short*)alloc(4 * 8 * 64 * 8 * 2);
    unsigned short* BpB = (unsigned short*)alloc(4 * 8 * 64 * 8 * 2);
    unsigned short* BpU = (unsigned short*)alloc(4 * 8 * 64 * 8 * 2);
    unsigned short* Bp2 = (unsigned short*)alloc(4 * 4 * 64 * 8 * 2);
    float* buf1 = (float*)alloc((size_t)N * H * 4);
    float* buf2 = (float*)alloc((size_t)N * H * 4);
    unsigned short* h3bf = (unsigned short*)alloc((size_t)N * H * 2);

    // graph build
    hipMemsetAsync(cnt, 0, (size_t)N * 4, stream);
    count_kernel<<<(E + 255) / 256, 256, 0, stream>>>(col, E, cnt);
    scan_sum_kernel<<<NB, 256, 0, stream>>>(cnt, N, bsum);
    scan_offsets_kernel<<<1, 64, 0, stream>>>(bsum, NB, boff, col_start, N);
    scan_write_kernel<<<NB, 256, 0, stream>>>(cnt, N, boff, col_start, cursor, dinv);
    scatter_kernel<<<(E + 255) / 256, 256, 0, stream>>>(row, col, E, cursor, csc_src);

    // classifier weight prep
    weff_kernel<<<64, 256, 0, stream>>>(We2, Wc1, Weff);
    bc1p_kernel<<<1, 128, 0, stream>>>(bc1, be2, Wc1, bc1p);
    packg_kernel<<<8, 256, 0, stream>>>(Wc1, BpA);                 // rows 0..127
    packg_kernel<<<8, 256, 0, stream>>>(Wc1 + 128 * 128, BpB);     // rows 128..255
    packg_kernel<<<8, 256, 0, stream>>>(Weff, BpU);
    pack2_kernel<<<4, 256, 0, stream>>>(Wc2, Bp2);

    // GCN (aggregate-then-transform; linearity of GCNConv)
    float* aggx = buf2;  // [N,8]
    aggx_kernel<<<(N * 8 + 255) / 256, 256, 0, stream>>>(x, col_start, csc_src, dinv, aggx, N);
    xform8_kernel<<<(N * 128 + 255) / 256, 256, 0, stream>>>(aggx, W1, b1, buf1, N);   // h1 -> buf1
    agg128_kernel<<<(N + 3) / 4, 256, 0, stream>>>(buf1, col_start, csc_src, dinv, buf2, N);
    xform128_kernel<<<(N + 7) / 8, 256, 0, stream>>>(buf2, W2, b2, buf1, N);           // h2 -> buf1
    agg128_kernel<<<(N + 3) / 4, 256, 0, stream>>>(buf1, col_start, csc_src, dinv, buf2, N);
    xform128bf_kernel<<<(N + 7) / 8, 256, 0, stream>>>(buf2, W3, b3, h3bf, N);         // h3 -> bf16

    // node-side classifier partials
    float* Pm = buf1;  // h2 dead
    float* Qm = buf2;  // agg3 dead
    pq_kernel<<<(N + 63) / 64, 256, 0, stream>>>(h3bf, BpA, BpB, bc1p, Pm, Qm, N);

    // fused classifier
    classifier_mfma<<<(E + 63) / 64, 256, 0, stream>>>(
        row, col, ea, We1, be1, Pm, Qm, BpU, Bp2, bc2, Wc3, bc3, out, E);
}

// Round 4
// 654.408 us; speedup vs baseline: 19.5244x; 1.3603x over previous
//
#include <hip/hip_runtime.h>
#include <math.h>

#define H 128
#define STC 152   // LDS stride (shorts) for bf16 A-tiles
#define SOT 136   // LDS stride (shorts) for staged bf16 output tiles
#define SPQS 132  // LDS stride (floats) for Spq

typedef __attribute__((ext_vector_type(8))) short short8;
typedef __attribute__((ext_vector_type(4))) float f32x4;

__device__ inline unsigned short f2bf(float f) {
    unsigned int u = __float_as_uint(f);
    return (unsigned short)((u + 0x7fffu + ((u >> 16) & 1u)) >> 16);
}
__device__ inline float bflo(unsigned int v) { return __uint_as_float(v << 16); }
__device__ inline float bfhi(unsigned int v) { return __uint_as_float(v & 0xffff0000u); }

__device__ inline void fma4(float4& acc, float a, const float4 w) {
    acc.x = fmaf(a, w.x, acc.x);
    acc.y = fmaf(a, w.y, acc.y);
    acc.z = fmaf(a, w.z, acc.z);
    acc.w = fmaf(a, w.w, acc.w);
}

// ---------------- graph build ----------------

__global__ void count_kernel(const int* __restrict__ col, int E, int* __restrict__ cnt) {
    int e = blockIdx.x * blockDim.x + threadIdx.x;
    if (e < E) atomicAdd(&cnt[col[e]], 1);
}

__global__ void scan_sum_kernel(const int* __restrict__ cnt, int N, int* __restrict__ bsum) {
    int b = blockIdx.x, t = threadIdx.x;
    int base = b * 1024 + t * 4;
    int s = 0;
#pragma unroll
    for (int g = 0; g < 4; ++g) {
        int i = base + g;
        if (i < N) s += cnt[i];
    }
    for (int off = 32; off >= 1; off >>= 1) s += __shfl_down(s, off, 64);
    __shared__ int ws[4];
    if ((t & 63) == 0) ws[t >> 6] = s;
    __syncthreads();
    if (t == 0) bsum[b] = ws[0] + ws[1] + ws[2] + ws[3];
}

__global__ void scan_offsets_kernel(const int* __restrict__ bsum, int nb,
                                    int* __restrict__ boff, int* __restrict__ col_start, int N) {
    int lane = threadIdx.x;
    int v = (lane < nb) ? bsum[lane] : 0;
    int incl = v;
    for (int off = 1; off < 64; off <<= 1) {
        int u = __shfl_up(incl, off, 64);
        if (lane >= off) incl += u;
    }
    if (lane < nb) boff[lane] = incl - v;
    if (lane == 63) col_start[N] = incl;
}

__global__ void scan_write_kernel(const int* __restrict__ cnt, int N, const int* __restrict__ boff,
                                  int* __restrict__ col_start, int* __restrict__ cursor,
                                  float* __restrict__ dinv) {
    int b = blockIdx.x, t = threadIdx.x;
    int lane = t & 63, wv = t >> 6;
    int base = b * 1024 + t * 4;
    int c[4];
    int s = 0;
#pragma unroll
    for (int g = 0; g < 4; ++g) {
        int i = base + g;
        c[g] = (i < N) ? cnt[i] : 0;
        s += c[g];
    }
    int incl = s;
    for (int off = 1; off < 64; off <<= 1) {
        int u = __shfl_up(incl, off, 64);
        if (lane >= off) incl += u;
    }
    __shared__ int ws[4];
    if (lane == 63) ws[wv] = incl;
    __syncthreads();
    int run = boff[b] + incl - s;
    for (int w = 0; w < wv; ++w) run += ws[w];
#pragma unroll
    for (int g = 0; g < 4; ++g) {
        int i = base + g;
        if (i < N) {
            col_start[i] = run;
            cursor[i] = run;
            dinv[i] = rsqrtf((float)(c[g] + 1));
            run += c[g];
        }
    }
}

__global__ void scatter_kernel(const int* __restrict__ row, const int* __restrict__ col, int E,
                               int* __restrict__ cursor, int* __restrict__ csc_src) {
    int e = blockIdx.x * blockDim.x + threadIdx.x;
    if (e < E) {
        int c = col[e];
        int p = atomicAdd(&cursor[c], 1);
        csc_src[p] = row[e];
    }
}

// ---------------- GCN: aggregate-then-transform (bf16 features) ----------------

__global__ void aggx_kernel(const float* __restrict__ x, const int* __restrict__ col_start,
                            const int* __restrict__ csc_src, const float* __restrict__ dinv,
                            float* __restrict__ aggx, int N) {
    int t = blockIdx.x * blockDim.x + threadIdx.x;
    int i = t >> 3, f = t & 7;
    if (i >= N) return;
    int s0 = col_start[i], s1 = col_start[i + 1];
    float acc = 0.f;
    for (int p = s0; p < s1; ++p) {
        int s = csc_src[p];
        acc = fmaf(dinv[s], x[s * 8 + f], acc);
    }
    float di = dinv[i];
    aggx[i * 8 + f] = fmaf(di, acc, di * di * x[i * 8 + f]);
}

// h1 = relu(aggx @ W1 + b1) -> bf16 (thread = node i, bf16-pair jp)
__global__ void xform8bf_kernel(const float* __restrict__ aggx, const float* __restrict__ W,
                                const float* __restrict__ b, unsigned int* __restrict__ out, int N) {
    int t = blockIdx.x * 256 + threadIdx.x;
    int i = t >> 6, jp = t & 63;
    if (i >= N) return;
    const float* ar = aggx + i * 8;
    int j0 = jp * 2;
    float a0 = b[j0], a1 = b[j0 + 1];
#pragma unroll
    for (int k = 0; k < 8; ++k) {
        float av = ar[k];
        a0 = fmaf(av, W[k * 128 + j0], a0);
        a1 = fmaf(av, W[k * 128 + j0 + 1], a1);
    }
    out[(size_t)i * 64 + jp] = (unsigned int)f2bf(fmaxf(a0, 0.f)) |
                               ((unsigned int)f2bf(fmaxf(a1, 0.f)) << 16);
}

// wave-per-node aggregation over bf16 rows, fp32 accumulate, bf16 out
__global__ __launch_bounds__(256) void agg128bf_kernel(
    const unsigned int* __restrict__ h, const int* __restrict__ col_start,
    const int* __restrict__ csc_src, const float* __restrict__ dinv,
    unsigned int* __restrict__ out, int N) {
    int wv = threadIdx.x >> 6, lane = threadIdx.x & 63;
    int i = blockIdx.x * 4 + wv;
    if (i >= N) return;
    int s0 = col_start[i], s1 = col_start[i + 1];
    float ax = 0.f, ay = 0.f;
    int p = s0;
    for (; p + 4 <= s1; p += 4) {
        int sa = csc_src[p], sb = csc_src[p + 1], sc = csc_src[p + 2], sd = csc_src[p + 3];
        float da = dinv[sa], db = dinv[sb], dc = dinv[sc], dd = dinv[sd];
        unsigned int va = h[(size_t)sa * 64 + lane];
        unsigned int vb = h[(size_t)sb * 64 + lane];
        unsigned int vc = h[(size_t)sc * 64 + lane];
        unsigned int vd = h[(size_t)sd * 64 + lane];
        ax = fmaf(da, bflo(va), ax); ay = fmaf(da, bfhi(va), ay);
        ax = fmaf(db, bflo(vb), ax); ay = fmaf(db, bfhi(vb), ay);
        ax = fmaf(dc, bflo(vc), ax); ay = fmaf(dc, bfhi(vc), ay);
        ax = fmaf(dd, bflo(vd), ax); ay = fmaf(dd, bfhi(vd), ay);
    }
    for (; p < s1; ++p) {
        int s = csc_src[p];
        float d = dinv[s];
        unsigned int v = h[(size_t)s * 64 + lane];
        ax = fmaf(d, bflo(v), ax); ay = fmaf(d, bfhi(v), ay);
    }
    float di = dinv[i];
    unsigned int vs = h[(size_t)i * 64 + lane];
    float rx = fmaf(di, ax, di * di * bflo(vs));
    float ry = fmaf(di, ay, di * di * bfhi(vs));
    out[(size_t)i * 64 + lane] = (unsigned int)f2bf(rx) | ((unsigned int)f2bf(ry) << 16);
}

// out = relu(in @ W + b) -> bf16, MFMA; in/out [N,128] bf16
__global__ __launch_bounds__(256) void xform_mfma_kernel(
    const unsigned short* __restrict__ in, const unsigned short* __restrict__ Bp,
    const float* __restrict__ b, unsigned short* __restrict__ out, int N) {
    __shared__ __align__(16) unsigned short sm[64 * STC];  // 19456 B; reused for Ot[64][SOT]
    int tid = threadIdx.x;
    int i0 = blockIdx.x * 64;
    for (int u = tid; u < 1024; u += 256) {
        int i = u >> 4, l = u & 15;
        int node = i0 + i; if (node >= N) node = N - 1;
        uint4 v = ((const uint4*)in)[(size_t)node * 16 + l];
        *(uint4*)&sm[i * STC + l * 8] = v;
    }
    __syncthreads();
    int lane = tid & 63, w = tid >> 6, lm = lane & 15, quad = lane >> 4;
    int nt0 = 2 * w, nt1 = 2 * w + 1;
    f32x4 acc0[4], acc1[4];
    {
        float bv0 = b[nt0 * 16 + lm], bv1 = b[nt1 * 16 + lm];
        for (int m = 0; m < 4; ++m)
            for (int r = 0; r < 4; ++r) { acc0[m][r] = bv0; acc1[m][r] = bv1; }
    }
#pragma unroll
    for (int s = 0; s < 4; ++s) {
        short8 b0 = *(const short8*)&Bp[((size_t)(s * 8 + nt0) * 64 + lane) * 8];
        short8 b1 = *(const short8*)&Bp[((size_t)(s * 8 + nt1) * 64 + lane) * 8];
#pragma unroll
        for (int m = 0; m < 4; ++m) {
            short8 afr = *(const short8*)&sm[(m * 16 + lm) * STC + s * 32 + quad * 8];
            acc0[m] = __builtin_amdgcn_mfma_f32_16x16x32_bf16(afr, b0, acc0[m], 0, 0, 0);
            acc1[m] = __builtin_amdgcn_mfma_f32_16x16x32_bf16(afr, b1, acc1[m], 0, 0, 0);
        }
    }
    __syncthreads();
    for (int m = 0; m < 4; ++m)
        for (int r = 0; r < 4; ++r) {
            int rw = m * 16 + quad * 4 + r;
            sm[rw * SOT + nt0 * 16 + lm] = f2bf(fmaxf(acc0[m][r], 0.f));
            sm[rw * SOT + nt1 * 16 + lm] = f2bf(fmaxf(acc1[m][r], 0.f));
        }
    __syncthreads();
    for (int u = tid; u < 1024; u += 256) {
        int i = u >> 4, l = u & 15;
        int node = i0 + i;
        if (node < N)
            *(uint4*)&out[(size_t)node * 128 + l * 8] = *(uint4*)&sm[i * SOT + l * 8];
    }
}

// ---------------- classifier weight prep ----------------

__global__ void weff_kernel(const float* __restrict__ We2, const float* __restrict__ Wc1,
                            float* __restrict__ Weff) {
    int idx = blockIdx.x * blockDim.x + threadIdx.x;
    int k = idx >> 7, c = idx & 127;
    float acc = 0.f;
    for (int j = 0; j < 128; ++j)
        acc = fmaf(We2[k * 128 + j], Wc1[(256 + j) * 128 + c], acc);
    Weff[idx] = acc;
}

__global__ void bc1p_kernel(const float* __restrict__ bc1, const float* __restrict__ be2,
                            const float* __restrict__ Wc1, float* __restrict__ bc1p) {
    int c = threadIdx.x;
    float acc = bc1[c];
    for (int j = 0; j < 128; ++j)
        acc = fmaf(be2[j], Wc1[(256 + j) * 128 + c], acc);
    bc1p[c] = acc;
}

__global__ void packg_kernel(const float* __restrict__ src, unsigned short* __restrict__ dst) {
    int idx = blockIdx.x * 256 + threadIdx.x;  // 2048
    int s = idx >> 9, nt = (idx >> 6) & 7, lane = idx & 63;
    int quad = lane >> 4, lm = lane & 15;
    int n = nt * 16 + lm, k0 = s * 32 + quad * 8;
    unsigned int p[4];
#pragma unroll
    for (int g = 0; g < 4; ++g) {
        p[g] = (unsigned int)f2bf(src[(k0 + 2 * g) * 128 + n]) |
               ((unsigned int)f2bf(src[(k0 + 2 * g + 1) * 128 + n]) << 16);
    }
    *(uint4*)&dst[(size_t)idx * 8] = make_uint4(p[0], p[1], p[2], p[3]);
}

__global__ void pack2_kernel(const float* __restrict__ Wc2, unsigned short* __restrict__ Bp2) {
    int idx = blockIdx.x * 256 + threadIdx.x;  // 1024
    int s = idx >> 8, nt = (idx >> 6) & 3, lane = idx & 63;
    int quad = lane >> 4, lm = lane & 15;
    int n = nt * 16 + lm, k0 = s * 32 + quad * 8;
    unsigned int p[4];
#pragma unroll
    for (int g = 0; g < 4; ++g) {
        p[g] = (unsigned int)f2bf(Wc2[(k0 + 2 * g) * 64 + n]) |
               ((unsigned int)f2bf(Wc2[(k0 + 2 * g + 1) * 64 + n]) << 16);
    }
    *(uint4*)&Bp2[(size_t)idx * 8] = make_uint4(p[0], p[1], p[2], p[3]);
}

// ---------------- P/Q precompute -> bf16 ----------------

__global__ __launch_bounds__(256) void pq_kernel(
    const unsigned short* __restrict__ hbf,
    const unsigned short* __restrict__ BpA, const unsigned short* __restrict__ BpB,
    const float* __restrict__ bc1p, unsigned short* __restrict__ P, unsigned short* __restrict__ Q,
    int N) {
    __shared__ __align__(16) unsigned char smem[34816];
    unsigned short* At = (unsigned short*)smem;        // [64][STC]
    unsigned short* Pst = (unsigned short*)smem;       // [64][SOT] (reuse)
    unsigned short* Qst = (unsigned short*)(smem + 17408);
    int tid = threadIdx.x;
    int i0 = blockIdx.x * 64;
    for (int u = tid; u < 1024; u += 256) {
        int i = u >> 4, l = u & 15;
        int node = i0 + i; if (node >= N) node = N - 1;
        uint4 v = ((const uint4*)hbf)[(size_t)node * 16 + l];
        *(uint4*)&At[i * STC + l * 8] = v;
    }
    __syncthreads();
    int lane = tid & 63, w = tid >> 6, lm = lane & 15, quad = lane >> 4;
    int half = w & 1;
    const unsigned short* Bp = (w >> 1) ? BpB : BpA;
    f32x4 acc[4][4];  // [nt][m]
    for (int nt = 0; nt < 4; ++nt) {
        float bv = (w >> 1) ? 0.f : bc1p[half * 64 + nt * 16 + lm];
        for (int m = 0; m < 4; ++m)
            for (int r = 0; r < 4; ++r) acc[nt][m][r] = bv;
    }
#pragma unroll
    for (int s = 0; s < 4; ++s) {
        short8 afr[4];
#pragma unroll
        for (int m = 0; m < 4; ++m)
            afr[m] = *(const short8*)&At[(m * 16 + lm) * STC + s * 32 + quad * 8];
#pragma unroll
        for (int nt = 0; nt < 4; ++nt) {
            short8 bfr = *(const short8*)&Bp[((size_t)(s * 8 + half * 4 + nt) * 64 + lane) * 8];
#pragma unroll
            for (int m = 0; m < 4; ++m)
                acc[nt][m] = __builtin_amdgcn_mfma_f32_16x16x32_bf16(afr[m], bfr, acc[nt][m], 0, 0, 0);
        }
    }
    __syncthreads();
    unsigned short* St = (w >> 1) ? Qst : Pst;
    for (int nt = 0; nt < 4; ++nt)
        for (int m = 0; m < 4; ++m)
            for (int r = 0; r < 4; ++r) {
                int rw = m * 16 + quad * 4 + r;
                St[rw * SOT + half * 64 + nt * 16 + lm] = f2bf(acc[nt][m][r]);
            }
    __syncthreads();
    for (int u = tid; u < 2048; u += 256) {
        int sel = u >> 10, i = (u >> 4) & 63, l = u & 15;
        int node = i0 + i;
        if (node < N) {
            unsigned short* dst = sel ? Q : P;
            const unsigned short* src = sel ? Qst : Pst;
            *(uint4*)&dst[(size_t)node * 128 + l * 8] = *(const uint4*)&src[i * SOT + l * 8];
        }
    }
}

// ---------------- fused classifier ----------------

__global__ __launch_bounds__(256, 3) void classifier_mfma(
    const int* __restrict__ row, const int* __restrict__ col, const float* __restrict__ ea,
    const float* __restrict__ We1, const float* __restrict__ be1,
    const unsigned short* __restrict__ P, const unsigned short* __restrict__ Q,
    const unsigned short* __restrict__ BpU, const unsigned short* __restrict__ Bp2,
    const float* __restrict__ bc2, const float* __restrict__ Wc3, const float* __restrict__ bc3,
    float* __restrict__ out, int E) {
    __shared__ __align__(16) unsigned char smem[53760];
    float* Spq = (float*)smem;                            // [64][SPQS] fp32
    unsigned short* z1 = (unsigned short*)smem;           // [64][STC] bf16 (reuse)
    unsigned short* At = (unsigned short*)(smem + 33792); // [64][STC] bf16
    float* z2 = (float*)(smem + 33792);                   // [64][69] fp32 (reuse)
    int* rS = (int*)(smem + 53248);
    int* cS = rS + 64;

    int tid = threadIdx.x;
    int e0 = blockIdx.x * 64;

    if (tid < 64) {
        int e = e0 + tid; if (e >= E) e = E - 1;
        rS[tid] = row[e]; cS[tid] = col[e];
    }
    __syncthreads();

    // stage Spq = P[row] + Q[col] (bf16 gather, fp32 add; bias folded in P)
    {
        const uint4* P4 = (const uint4*)P;
        const uint4* Q4 = (const uint4*)Q;
        for (int u = tid; u < 1024; u += 256) {
            int i = u >> 4, l = u & 15;
            uint4 pv = P4[(size_t)rS[i] * 16 + l];
            uint4 qv = Q4[(size_t)cS[i] * 16 + l];
            float4 r0, r1;
            r0.x = bflo(pv.x) + bflo(qv.x); r0.y = bfhi(pv.x) + bfhi(qv.x);
            r0.z = bflo(pv.y) + bflo(qv.y); r0.w = bfhi(pv.y) + bfhi(qv.y);
            r1.x = bflo(pv.z) + bflo(qv.z); r1.y = bfhi(pv.z) + bfhi(qv.z);
            r1.z = bflo(pv.w) + bflo(qv.w); r1.w = bfhi(pv.w) + bfhi(qv.w);
            *(float4*)&Spq[i * SPQS + l * 8] = r0;
            *(float4*)&Spq[i * SPQS + l * 8 + 4] = r1;
        }
    }
    // stage t = relu(ea@We1+be1) -> At (bf16)
    {
        int i = tid >> 2, jv0 = (tid & 3) * 32;
        int e = e0 + i; if (e >= E) e = E - 1;
        float4 a = ((const float4*)ea)[e];
        const float4* W14 = (const float4*)We1;
        const float4* b14 = (const float4*)be1;
        for (int g = 0; g < 4; ++g) {
            int j0 = jv0 + g * 8, q = j0 >> 2;
            float4 r0 = b14[q], r1 = b14[q + 1];
            fma4(r0, a.x, W14[q]);      fma4(r1, a.x, W14[q + 1]);
            fma4(r0, a.y, W14[32 + q]); fma4(r1, a.y, W14[32 + q + 1]);
            fma4(r0, a.z, W14[64 + q]); fma4(r1, a.z, W14[64 + q + 1]);
            fma4(r0, a.w, W14[96 + q]); fma4(r1, a.w, W14[96 + q + 1]);
            unsigned int p0 = (unsigned int)f2bf(fmaxf(r0.x, 0.f)) | ((unsigned int)f2bf(fmaxf(r0.y, 0.f)) << 16);
            unsigned int p1 = (unsigned int)f2bf(fmaxf(r0.z, 0.f)) | ((unsigned int)f2bf(fmaxf(r0.w, 0.f)) << 16);
            unsigned int p2 = (unsigned int)f2bf(fmaxf(r1.x, 0.f)) | ((unsigned int)f2bf(fmaxf(r1.y, 0.f)) << 16);
            unsigned int p3 = (unsigned int)f2bf(fmaxf(r1.z, 0.f)) | ((unsigned int)f2bf(fmaxf(r1.w, 0.f)) << 16);
            *(uint4*)&At[i * STC + j0] = make_uint4(p0, p1, p2, p3);
        }
    }
    __syncthreads();

    int lane = tid & 63, w = tid >> 6, lm = lane & 15, quad = lane >> 4;

    // GEMM_t: U = t @ Weff (K=128); wave w owns n-tiles 2w, 2w+1
    f32x4 acc0[4], acc1[4];
    for (int m = 0; m < 4; ++m)
        for (int r = 0; r < 4; ++r) { acc0[m][r] = 0.f; acc1[m][r] = 0.f; }
#pragma unroll
    for (int s = 0; s < 4; ++s) {
        short8 b0 = *(const short8*)&BpU[((size_t)(s * 8 + 2 * w) * 64 + lane) * 8];
        short8 b1 = *(const short8*)&BpU[((size_t)(s * 8 + 2 * w + 1) * 64 + lane) * 8];
#pragma unroll
        for (int m = 0; m < 4; ++m) {
            short8 afr = *(const short8*)&At[(m * 16 + lm) * STC + s * 32 + quad * 8];
            acc0[m] = __builtin_amdgcn_mfma_f32_16x16x32_bf16(afr, b0, acc0[m], 0, 0, 0);
            acc1[m] = __builtin_amdgcn_mfma_f32_16x16x32_bf16(afr, b1, acc1[m], 0, 0, 0);
        }
    }
    // z1 = relu(U + Spq)
    for (int m = 0; m < 4; ++m)
        for (int r = 0; r < 4; ++r) {
            int rw = m * 16 + quad * 4 + r;
            acc0[m][r] = fmaxf(acc0[m][r] + Spq[rw * SPQS + 32 * w + lm], 0.f);
            acc1[m][r] = fmaxf(acc1[m][r] + Spq[rw * SPQS + 32 * w + 16 + lm], 0.f);
        }
    __syncthreads();
    for (int m = 0; m < 4; ++m)
        for (int r = 0; r < 4; ++r) {
            int rw = m * 16 + quad * 4 + r;
            z1[rw * STC + 32 * w + lm]      = f2bf(acc0[m][r]);
            z1[rw * STC + 32 * w + 16 + lm] = f2bf(acc1[m][r]);
        }
    __syncthreads();

    // GEMM2: z2 = relu(z1 @ Wc2 + bc2); wave w owns n-tile w
    {
        f32x4 acc2[4];
        float bv = bc2[w * 16 + lm];
        for (int m = 0; m < 4; ++m)
            for (int r = 0; r < 4; ++r) acc2[m][r] = bv;
#pragma unroll
        for (int s = 0; s < 4; ++s) {
            short8 b = *(const short8*)&Bp2[((size_t)(s * 4 + w) * 64 + lane) * 8];
#pragma unroll
            for (int m = 0; m < 4; ++m) {
                short8 afr = *(const short8*)&z1[(m * 16 + lm) * STC + s * 32 + quad * 8];
                acc2[m] = __builtin_amdgcn_mfma_f32_16x16x32_bf16(afr, b, acc2[m], 0, 0, 0);
            }
        }
        for (int m = 0; m < 4; ++m)
            for (int r = 0; r < 4; ++r)
                z2[(m * 16 + quad * 4 + r) * 69 + w * 16 + lm] = fmaxf(acc2[m][r], 0.f);
    }
    __syncthreads();

    if (tid < 64) {
        int e = e0 + tid;
        if (e < E) {
            const float* zr = z2 + tid * 69;
            float l0 = bc3[0], l1 = bc3[1];
            for (int k = 0; k < 64; ++k) {
                float z = zr[k];
                l0 = fmaf(z, Wc3[2 * k], l0);
                l1 = fmaf(z, Wc3[2 * k + 1], l1);
            }
            float m = fmaxf(l0, l1);
            float lse = m + logf(expf(l0 - m) + expf(l1 - m));
            ((float2*)out)[e] = make_float2(l0 - lse, l1 - lse);
        }
    }
}

// ---------------- launch ----------------

extern "C" void kernel_launch(void* const* d_in, const int* in_sizes, int n_in,
                              void* d_out, int out_size, void* d_ws, size_t ws_size,
                              hipStream_t stream) {
    const float* x   = (const float*)d_in[0];
    const int*   ei  = (const int*)d_in[1];
    const float* ea  = (const float*)d_in[2];
    const float* W1  = (const float*)d_in[3];
    const float* b1  = (const float*)d_in[4];
    const float* W2  = (const float*)d_in[5];
    const float* b2  = (const float*)d_in[6];
    const float* W3  = (const float*)d_in[7];
    const float* b3  = (const float*)d_in[8];
    const float* We1 = (const float*)d_in[9];
    const float* be1 = (const float*)d_in[10];
    const float* We2 = (const float*)d_in[11];
    const float* be2 = (const float*)d_in[12];
    const float* Wc1 = (const float*)d_in[13];
    const float* bc1 = (const float*)d_in[14];
    const float* Wc2 = (const float*)d_in[15];
    const float* bc2 = (const float*)d_in[16];
    const float* Wc3 = (const float*)d_in[17];
    const float* bc3 = (const float*)d_in[18];
    float* out = (float*)d_out;

    int N = in_sizes[0] / 8;
    int E = in_sizes[1] / 2;
    const int* row = ei;
    const int* col = ei + E;
    int NB = (N + 1023) / 1024;

    char* w = (char*)d_ws;
    auto alloc = [&](size_t bytes) { void* p = (void*)w; w += (bytes + 255) & ~(size_t)255; return p; };
    int*   cnt       = (int*)alloc((size_t)N * 4);
    int*   col_start = (int*)alloc((size_t)(N + 1) * 4);
    int*   cursor    = (int*)alloc((size_t)N * 4);
    int*   csc_src   = (int*)alloc((size_t)E * 4);
    float* dinv      = (float*)alloc((size_t)N * 4);
    int*   bsum      = (int*)alloc(64 * 4);
    int*   boff      = (int*)alloc(64 * 4);
    float* Weff      = (float*)alloc(128 * 128 * 4);
    float* bc1p      = (float*)alloc(128 * 4);
    unsigned short* BpA  = (unsigned short*)alloc(32768);
    unsigned short* BpB  = (unsigned short*)alloc(32768);
    unsigned short* BpU  = (unsigned short*)alloc(32768);
    unsigned short* BpW2 = (unsigned short*)alloc(32768);
    unsigned short* BpW3 = (unsigned short*)alloc(32768);
    unsigned short* Bp2  = (unsigned short*)alloc(16384);
    float* aggx = (float*)alloc((size_t)N * 8 * 4);
    unsigned short* bufA = (unsigned short*)alloc((size_t)N * H * 2);
    unsigned short* bufB = (unsigned short*)alloc((size_t)N * H * 2);
    unsigned short* Pm   = (unsigned short*)alloc((size_t)N * H * 2);
    unsigned short* Qm   = (unsigned short*)alloc((size_t)N * H * 2);

    // graph build
    hipMemsetAsync(cnt, 0, (size_t)N * 4, stream);
    count_kernel<<<(E + 255) / 256, 256, 0, stream>>>(col, E, cnt);
    scan_sum_kernel<<<NB, 256, 0, stream>>>(cnt, N, bsum);
    scan_offsets_kernel<<<1, 64, 0, stream>>>(bsum, NB, boff, col_start, N);
    scan_write_kernel<<<NB, 256, 0, stream>>>(cnt, N, boff, col_start, cursor, dinv);
    scatter_kernel<<<(E + 255) / 256, 256, 0, stream>>>(row, col, E, cursor, csc_src);

    // weight prep
    weff_kernel<<<64, 256, 0, stream>>>(We2, Wc1, Weff);
    bc1p_kernel<<<1, 128, 0, stream>>>(bc1, be2, Wc1, bc1p);
    packg_kernel<<<8, 256, 0, stream>>>(Wc1, BpA);
    packg_kernel<<<8, 256, 0, stream>>>(Wc1 + 128 * 128, BpB);
    packg_kernel<<<8, 256, 0, stream>>>(Weff, BpU);
    packg_kernel<<<8, 256, 0, stream>>>(W2, BpW2);
    packg_kernel<<<8, 256, 0, stream>>>(W3, BpW3);
    pack2_kernel<<<4, 256, 0, stream>>>(Wc2, Bp2);

    // GCN: aggregate-then-transform, bf16 features
    aggx_kernel<<<(N * 8 + 255) / 256, 256, 0, stream>>>(x, col_start, csc_src, dinv, aggx, N);
    xform8bf_kernel<<<(N * 64 + 255) / 256, 256, 0, stream>>>(aggx, W1, b1, (unsigned int*)bufA, N);  // h1
    agg128bf_kernel<<<(N + 3) / 4, 256, 0, stream>>>((const unsigned int*)bufA, col_start, csc_src, dinv,
                                                     (unsigned int*)bufB, N);                          // agg2
    xform_mfma_kernel<<<(N + 63) / 64, 256, 0, stream>>>(bufB, BpW2, b2, bufA, N);                     // h2
    agg128bf_kernel<<<(N + 3) / 4, 256, 0, stream>>>((const unsigned int*)bufA, col_start, csc_src, dinv,
                                                     (unsigned int*)bufB, N);                          // agg3
    xform_mfma_kernel<<<(N + 63) / 64, 256, 0, stream>>>(bufB, BpW3, b3, bufA, N);                     // h3

    // node-side classifier partials (bf16)
    pq_kernel<<<(N + 63) / 64, 256, 0, stream>>>(bufA, BpA, BpB, bc1p, Pm, Qm, N);

    // fused classifier
    classifier_mfma<<<(E + 63) / 64, 256, 0, stream>>>(
        row, col, ea, We1, be1, Pm, Qm, BpU, Bp2, bc2, Wc3, bc3, out, E);
}

// Round 5
// 648.555 us; speedup vs baseline: 19.7006x; 1.0090x over previous
//
#include <hip/hip_runtime.h>
#include <math.h>

#define H 128
#define STC 152   // LDS stride (shorts) for bf16 A-tiles
#define SOT 136   // LDS stride (shorts) for staged bf16 output tiles
#define SPQ 136   // LDS stride (shorts) for bf16 Spq
#define Z2S 69    // LDS stride (floats) for z2 (odd -> 2-way banks)

typedef __attribute__((ext_vector_type(8))) short short8;
typedef __attribute__((ext_vector_type(4))) float f32x4;

__device__ inline unsigned short f2bf(float f) {
    unsigned int u = __float_as_uint(f);
    return (unsigned short)((u + 0x7fffu + ((u >> 16) & 1u)) >> 16);
}
__device__ inline float bflo(unsigned int v) { return __uint_as_float(v << 16); }
__device__ inline float bfhi(unsigned int v) { return __uint_as_float(v & 0xffff0000u); }
__device__ inline float bf2f(unsigned short v) { return __uint_as_float(((unsigned int)v) << 16); }

__device__ inline void fma4(float4& acc, float a, const float4 w) {
    acc.x = fmaf(a, w.x, acc.x);
    acc.y = fmaf(a, w.y, acc.y);
    acc.z = fmaf(a, w.z, acc.z);
    acc.w = fmaf(a, w.w, acc.w);
}

// ---------------- graph build ----------------

__global__ void count_kernel(const int* __restrict__ col, int E, int* __restrict__ cnt) {
    int e = blockIdx.x * blockDim.x + threadIdx.x;
    if (e < E) atomicAdd(&cnt[col[e]], 1);
}

__global__ void scan_sum_kernel(const int* __restrict__ cnt, int N, int* __restrict__ bsum) {
    int b = blockIdx.x, t = threadIdx.x;
    int base = b * 1024 + t * 4;
    int s = 0;
#pragma unroll
    for (int g = 0; g < 4; ++g) {
        int i = base + g;
        if (i < N) s += cnt[i];
    }
    for (int off = 32; off >= 1; off >>= 1) s += __shfl_down(s, off, 64);
    __shared__ int ws[4];
    if ((t & 63) == 0) ws[t >> 6] = s;
    __syncthreads();
    if (t == 0) bsum[b] = ws[0] + ws[1] + ws[2] + ws[3];
}

__global__ void scan_offsets_kernel(const int* __restrict__ bsum, int nb,
                                    int* __restrict__ boff, int* __restrict__ col_start, int N) {
    int lane = threadIdx.x;
    int v = (lane < nb) ? bsum[lane] : 0;
    int incl = v;
    for (int off = 1; off < 64; off <<= 1) {
        int u = __shfl_up(incl, off, 64);
        if (lane >= off) incl += u;
    }
    if (lane < nb) boff[lane] = incl - v;
    if (lane == 63) col_start[N] = incl;
}

__global__ void scan_write_kernel(const int* __restrict__ cnt, int N, const int* __restrict__ boff,
                                  int* __restrict__ col_start, int* __restrict__ cursor,
                                  float* __restrict__ dinv) {
    int b = blockIdx.x, t = threadIdx.x;
    int lane = t & 63, wv = t >> 6;
    int base = b * 1024 + t * 4;
    int c[4];
    int s = 0;
#pragma unroll
    for (int g = 0; g < 4; ++g) {
        int i = base + g;
        c[g] = (i < N) ? cnt[i] : 0;
        s += c[g];
    }
    int incl = s;
    for (int off = 1; off < 64; off <<= 1) {
        int u = __shfl_up(incl, off, 64);
        if (lane >= off) incl += u;
    }
    __shared__ int ws[4];
    if (lane == 63) ws[wv] = incl;
    __syncthreads();
    int run = boff[b] + incl - s;
    for (int w = 0; w < wv; ++w) run += ws[w];
#pragma unroll
    for (int g = 0; g < 4; ++g) {
        int i = base + g;
        if (i < N) {
            col_start[i] = run;
            cursor[i] = run;
            dinv[i] = rsqrtf((float)(c[g] + 1));
            run += c[g];
        }
    }
}

__global__ void scatter_kernel(const int* __restrict__ row, const int* __restrict__ col, int E,
                               int* __restrict__ cursor, int* __restrict__ csc_src) {
    int e = blockIdx.x * blockDim.x + threadIdx.x;
    if (e < E) {
        int c = col[e];
        int p = atomicAdd(&cursor[c], 1);
        csc_src[p] = row[e];
    }
}

// ---------------- GCN: aggregate-then-transform (bf16 dinv-prescaled features) ----------------

__global__ void aggx_kernel(const float* __restrict__ x, const int* __restrict__ col_start,
                            const int* __restrict__ csc_src, const float* __restrict__ dinv,
                            float* __restrict__ aggx, int N) {
    int t = blockIdx.x * blockDim.x + threadIdx.x;
    int i = t >> 3, f = t & 7;
    if (i >= N) return;
    int s0 = col_start[i], s1 = col_start[i + 1];
    float acc = 0.f;
    for (int p = s0; p < s1; ++p) {
        int s = csc_src[p];
        acc = fmaf(dinv[s], x[s * 8 + f], acc);
    }
    float di = dinv[i];
    aggx[i * 8 + f] = fmaf(di, acc, di * di * x[i * 8 + f]);
}

// h1d = dinv * relu(aggx @ W1 + b1) -> bf16
__global__ void xform8bf_kernel(const float* __restrict__ aggx, const float* __restrict__ W,
                                const float* __restrict__ b, const float* __restrict__ dinv,
                                unsigned int* __restrict__ out, int N) {
    int t = blockIdx.x * 256 + threadIdx.x;
    int i = t >> 6, jp = t & 63;
    if (i >= N) return;
    const float* ar = aggx + i * 8;
    float sc = dinv[i];
    int j0 = jp * 2;
    float a0 = b[j0], a1 = b[j0 + 1];
#pragma unroll
    for (int k = 0; k < 8; ++k) {
        float av = ar[k];
        a0 = fmaf(av, W[k * 128 + j0], a0);
        a1 = fmaf(av, W[k * 128 + j0 + 1], a1);
    }
    out[(size_t)i * 64 + jp] = (unsigned int)f2bf(sc * fmaxf(a0, 0.f)) |
                               ((unsigned int)f2bf(sc * fmaxf(a1, 0.f)) << 16);
}

// wave-per-node row-sum of prescaled bf16 rows: out = di * (sum_neighbors hd + hd_self)
__global__ __launch_bounds__(256) void agg128bf_kernel(
    const unsigned int* __restrict__ hd, const int* __restrict__ col_start,
    const int* __restrict__ csc_src, const float* __restrict__ dinv,
    unsigned int* __restrict__ out, int N) {
    int wv = threadIdx.x >> 6, lane = threadIdx.x & 63;
    int i = blockIdx.x * 4 + wv;
    if (i >= N) return;
    int s0 = col_start[i], s1 = col_start[i + 1];
    float ax = 0.f, ay = 0.f;
    int p = s0;
    for (; p + 8 <= s1; p += 8) {
        unsigned int v0 = hd[(size_t)csc_src[p + 0] * 64 + lane];
        unsigned int v1 = hd[(size_t)csc_src[p + 1] * 64 + lane];
        unsigned int v2 = hd[(size_t)csc_src[p + 2] * 64 + lane];
        unsigned int v3 = hd[(size_t)csc_src[p + 3] * 64 + lane];
        unsigned int v4 = hd[(size_t)csc_src[p + 4] * 64 + lane];
        unsigned int v5 = hd[(size_t)csc_src[p + 5] * 64 + lane];
        unsigned int v6 = hd[(size_t)csc_src[p + 6] * 64 + lane];
        unsigned int v7 = hd[(size_t)csc_src[p + 7] * 64 + lane];
        ax += bflo(v0) + bflo(v1) + bflo(v2) + bflo(v3) + bflo(v4) + bflo(v5) + bflo(v6) + bflo(v7);
        ay += bfhi(v0) + bfhi(v1) + bfhi(v2) + bfhi(v3) + bfhi(v4) + bfhi(v5) + bfhi(v6) + bfhi(v7);
    }
    for (; p < s1; ++p) {
        unsigned int v = hd[(size_t)csc_src[p] * 64 + lane];
        ax += bflo(v); ay += bfhi(v);
    }
    float di = dinv[i];
    unsigned int vs = hd[(size_t)i * 64 + lane];
    float rx = di * (ax + bflo(vs));
    float ry = di * (ay + bfhi(vs));
    out[(size_t)i * 64 + lane] = (unsigned int)f2bf(rx) | ((unsigned int)f2bf(ry) << 16);
}

// out = [scale] * relu(in @ W + b) -> bf16, MFMA
__global__ __launch_bounds__(256) void xform_mfma_kernel(
    const unsigned short* __restrict__ in, const unsigned short* __restrict__ Bp,
    const float* __restrict__ b, const float* __restrict__ scale,
    unsigned short* __restrict__ out, int N) {
    __shared__ __align__(16) unsigned short sm[64 * STC];
    int tid = threadIdx.x;
    int i0 = blockIdx.x * 64;
    for (int u = tid; u < 1024; u += 256) {
        int i = u >> 4, l = u & 15;
        int node = i0 + i; if (node >= N) node = N - 1;
        uint4 v = ((const uint4*)in)[(size_t)node * 16 + l];
        *(uint4*)&sm[i * STC + l * 8] = v;
    }
    __syncthreads();
    int lane = tid & 63, w = tid >> 6, lm = lane & 15, quad = lane >> 4;
    int nt0 = 2 * w, nt1 = 2 * w + 1;
    f32x4 acc0[4], acc1[4];
    {
        float bv0 = b[nt0 * 16 + lm], bv1 = b[nt1 * 16 + lm];
        for (int m = 0; m < 4; ++m)
            for (int r = 0; r < 4; ++r) { acc0[m][r] = bv0; acc1[m][r] = bv1; }
    }
#pragma unroll
    for (int s = 0; s < 4; ++s) {
        short8 b0 = *(const short8*)&Bp[((size_t)(s * 8 + nt0) * 64 + lane) * 8];
        short8 b1 = *(const short8*)&Bp[((size_t)(s * 8 + nt1) * 64 + lane) * 8];
#pragma unroll
        for (int m = 0; m < 4; ++m) {
            short8 afr = *(const short8*)&sm[(m * 16 + lm) * STC + s * 32 + quad * 8];
            acc0[m] = __builtin_amdgcn_mfma_f32_16x16x32_bf16(afr, b0, acc0[m], 0, 0, 0);
            acc1[m] = __builtin_amdgcn_mfma_f32_16x16x32_bf16(afr, b1, acc1[m], 0, 0, 0);
        }
    }
    __syncthreads();
    for (int m = 0; m < 4; ++m)
        for (int r = 0; r < 4; ++r) {
            int rw = m * 16 + quad * 4 + r;
            int node = i0 + rw; if (node >= N) node = N - 1;
            float sc = scale ? scale[node] : 1.f;
            sm[rw * SOT + nt0 * 16 + lm] = f2bf(sc * fmaxf(acc0[m][r], 0.f));
            sm[rw * SOT + nt1 * 16 + lm] = f2bf(sc * fmaxf(acc1[m][r], 0.f));
        }
    __syncthreads();
    for (int u = tid; u < 1024; u += 256) {
        int i = u >> 4, l = u & 15;
        int node = i0 + i;
        if (node < N)
            *(uint4*)&out[(size_t)node * 128 + l * 8] = *(uint4*)&sm[i * SOT + l * 8];
    }
}

// ---------------- classifier weight prep ----------------

__global__ void weff_kernel(const float* __restrict__ We2, const float* __restrict__ Wc1,
                            float* __restrict__ Weff) {
    int idx = blockIdx.x * blockDim.x + threadIdx.x;
    int k = idx >> 7, c = idx & 127;
    float acc = 0.f;
    for (int j = 0; j < 128; ++j)
        acc = fmaf(We2[k * 128 + j], Wc1[(256 + j) * 128 + c], acc);
    Weff[idx] = acc;
}

__global__ void bc1p_kernel(const float* __restrict__ bc1, const float* __restrict__ be2,
                            const float* __restrict__ Wc1, float* __restrict__ bc1p) {
    int c = threadIdx.x;
    float acc = bc1[c];
    for (int j = 0; j < 128; ++j)
        acc = fmaf(be2[j], Wc1[(256 + j) * 128 + c], acc);
    bc1p[c] = acc;
}

__global__ void packg_kernel(const float* __restrict__ src, unsigned short* __restrict__ dst) {
    int idx = blockIdx.x * 256 + threadIdx.x;  // 2048
    int s = idx >> 9, nt = (idx >> 6) & 7, lane = idx & 63;
    int quad = lane >> 4, lm = lane & 15;
    int n = nt * 16 + lm, k0 = s * 32 + quad * 8;
    unsigned int p[4];
#pragma unroll
    for (int g = 0; g < 4; ++g) {
        p[g] = (unsigned int)f2bf(src[(k0 + 2 * g) * 128 + n]) |
               ((unsigned int)f2bf(src[(k0 + 2 * g + 1) * 128 + n]) << 16);
    }
    *(uint4*)&dst[(size_t)idx * 8] = make_uint4(p[0], p[1], p[2], p[3]);
}

__global__ void pack2_kernel(const float* __restrict__ Wc2, unsigned short* __restrict__ Bp2) {
    int idx = blockIdx.x * 256 + threadIdx.x;  // 1024
    int s = idx >> 8, nt = (idx >> 6) & 3, lane = idx & 63;
    int quad = lane >> 4, lm = lane & 15;
    int n = nt * 16 + lm, k0 = s * 32 + quad * 8;
    unsigned int p[4];
#pragma unroll
    for (int g = 0; g < 4; ++g) {
        p[g] = (unsigned int)f2bf(Wc2[(k0 + 2 * g) * 64 + n]) |
               ((unsigned int)f2bf(Wc2[(k0 + 2 * g + 1) * 64 + n]) << 16);
    }
    *(uint4*)&Bp2[(size_t)idx * 8] = make_uint4(p[0], p[1], p[2], p[3]);
}

// ---------------- P/Q precompute -> bf16 ----------------

__global__ __launch_bounds__(256) void pq_kernel(
    const unsigned short* __restrict__ hbf,
    const unsigned short* __restrict__ BpA, const unsigned short* __restrict__ BpB,
    const float* __restrict__ bc1p, unsigned short* __restrict__ P, unsigned short* __restrict__ Q,
    int N) {
    __shared__ __align__(16) unsigned char smem[34816];
    unsigned short* At = (unsigned short*)smem;        // [64][STC]
    unsigned short* Pst = (unsigned short*)smem;       // [64][SOT] (reuse)
    unsigned short* Qst = (unsigned short*)(smem + 17408);
    int tid = threadIdx.x;
    int i0 = blockIdx.x * 64;
    for (int u = tid; u < 1024; u += 256) {
        int i = u >> 4, l = u & 15;
        int node = i0 + i; if (node >= N) node = N - 1;
        uint4 v = ((const uint4*)hbf)[(size_t)node * 16 + l];
        *(uint4*)&At[i * STC + l * 8] = v;
    }
    __syncthreads();
    int lane = tid & 63, w = tid >> 6, lm = lane & 15, quad = lane >> 4;
    int half = w & 1;
    const unsigned short* Bp = (w >> 1) ? BpB : BpA;
    f32x4 acc[4][4];  // [nt][m]
    for (int nt = 0; nt < 4; ++nt) {
        float bv = (w >> 1) ? 0.f : bc1p[half * 64 + nt * 16 + lm];
        for (int m = 0; m < 4; ++m)
            for (int r = 0; r < 4; ++r) acc[nt][m][r] = bv;
    }
#pragma unroll
    for (int s = 0; s < 4; ++s) {
        short8 afr[4];
#pragma unroll
        for (int m = 0; m < 4; ++m)
            afr[m] = *(const short8*)&At[(m * 16 + lm) * STC + s * 32 + quad * 8];
#pragma unroll
        for (int nt = 0; nt < 4; ++nt) {
            short8 bfr = *(const short8*)&Bp[((size_t)(s * 8 + half * 4 + nt) * 64 + lane) * 8];
#pragma unroll
            for (int m = 0; m < 4; ++m)
                acc[nt][m] = __builtin_amdgcn_mfma_f32_16x16x32_bf16(afr[m], bfr, acc[nt][m], 0, 0, 0);
        }
    }
    __syncthreads();
    unsigned short* St = (w >> 1) ? Qst : Pst;
    for (int nt = 0; nt < 4; ++nt)
        for (int m = 0; m < 4; ++m)
            for (int r = 0; r < 4; ++r) {
                int rw = m * 16 + quad * 4 + r;
                St[rw * SOT + half * 64 + nt * 16 + lm] = f2bf(acc[nt][m][r]);
            }
    __syncthreads();
    for (int u = tid; u < 2048; u += 256) {
        int sel = u >> 10, i = (u >> 4) & 63, l = u & 15;
        int node = i0 + i;
        if (node < N) {
            unsigned short* dst = sel ? Q : P;
            const unsigned short* src = sel ? Qst : Pst;
            *(uint4*)&dst[(size_t)node * 128 + l * 8] = *(const uint4*)&src[i * SOT + l * 8];
        }
    }
}

// ---------------- fused classifier (37.6 KB LDS -> 4 blocks/CU) ----------------

__global__ __launch_bounds__(256, 4) void classifier_mfma(
    const int* __restrict__ row, const int* __restrict__ col, const float* __restrict__ ea,
    const float* __restrict__ We1, const float* __restrict__ be1,
    const unsigned short* __restrict__ P, const unsigned short* __restrict__ Q,
    const unsigned short* __restrict__ BpU, const unsigned short* __restrict__ Bp2,
    const float* __restrict__ bc2, const float* __restrict__ Wc3, const float* __restrict__ bc3,
    float* __restrict__ out, int E) {
    __shared__ __align__(16) unsigned char smem[37632];
    unsigned short* SpqB = (unsigned short*)smem;         // [64][SPQ] bf16
    float* z2 = (float*)smem;                             // [64][Z2S] fp32 (reuse)
    unsigned short* At = (unsigned short*)(smem + 17664); // [64][STC] bf16
    unsigned short* z1 = At;                              // reuse after GEMM_t
    float* part = (float*)(smem + 17664);                 // [4][64] logits partials (reuse)
    int* rS = (int*)(smem + 37120);
    int* cS = rS + 64;

    int tid = threadIdx.x;
    int e0 = blockIdx.x * 64;

    if (tid < 64) {
        int e = e0 + tid; if (e >= E) e = E - 1;
        rS[tid] = row[e]; cS[tid] = col[e];
    }
    __syncthreads();

    // stage Spq = bf16(P[row] + Q[col])  (bias folded in P)
    {
        const uint4* P4 = (const uint4*)P;
        const uint4* Q4 = (const uint4*)Q;
        for (int u = tid; u < 1024; u += 256) {
            int i = u >> 4, l = u & 15;
            uint4 pv = P4[(size_t)rS[i] * 16 + l];
            uint4 qv = Q4[(size_t)cS[i] * 16 + l];
            unsigned int o0 = (unsigned int)f2bf(bflo(pv.x) + bflo(qv.x)) |
                              ((unsigned int)f2bf(bfhi(pv.x) + bfhi(qv.x)) << 16);
            unsigned int o1 = (unsigned int)f2bf(bflo(pv.y) + bflo(qv.y)) |
                              ((unsigned int)f2bf(bfhi(pv.y) + bfhi(qv.y)) << 16);
            unsigned int o2 = (unsigned int)f2bf(bflo(pv.z) + bflo(qv.z)) |
                              ((unsigned int)f2bf(bfhi(pv.z) + bfhi(qv.z)) << 16);
            unsigned int o3 = (unsigned int)f2bf(bflo(pv.w) + bflo(qv.w)) |
                              ((unsigned int)f2bf(bfhi(pv.w) + bfhi(qv.w)) << 16);
            *(uint4*)&SpqB[i * SPQ + l * 8] = make_uint4(o0, o1, o2, o3);
        }
    }
    // stage t = relu(ea@We1+be1) -> At (bf16)
    {
        int i = tid >> 2, jv0 = (tid & 3) * 32;
        int e = e0 + i; if (e >= E) e = E - 1;
        float4 a = ((const float4*)ea)[e];
        const float4* W14 = (const float4*)We1;
        const float4* b14 = (const float4*)be1;
        for (int g = 0; g < 4; ++g) {
            int j0 = jv0 + g * 8, q = j0 >> 2;
            float4 r0 = b14[q], r1 = b14[q + 1];
            fma4(r0, a.x, W14[q]);      fma4(r1, a.x, W14[q + 1]);
            fma4(r0, a.y, W14[32 + q]); fma4(r1, a.y, W14[32 + q + 1]);
            fma4(r0, a.z, W14[64 + q]); fma4(r1, a.z, W14[64 + q + 1]);
            fma4(r0, a.w, W14[96 + q]); fma4(r1, a.w, W14[96 + q + 1]);
            unsigned int p0 = (unsigned int)f2bf(fmaxf(r0.x, 0.f)) | ((unsigned int)f2bf(fmaxf(r0.y, 0.f)) << 16);
            unsigned int p1 = (unsigned int)f2bf(fmaxf(r0.z, 0.f)) | ((unsigned int)f2bf(fmaxf(r0.w, 0.f)) << 16);
            unsigned int p2 = (unsigned int)f2bf(fmaxf(r1.x, 0.f)) | ((unsigned int)f2bf(fmaxf(r1.y, 0.f)) << 16);
            unsigned int p3 = (unsigned int)f2bf(fmaxf(r1.z, 0.f)) | ((unsigned int)f2bf(fmaxf(r1.w, 0.f)) << 16);
            *(uint4*)&At[i * STC + j0] = make_uint4(p0, p1, p2, p3);
        }
    }
    __syncthreads();

    int lane = tid & 63, w = tid >> 6, lm = lane & 15, quad = lane >> 4;

    // GEMM_t: U = t @ Weff (K=128); wave w owns n-tiles 2w, 2w+1
    f32x4 acc0[4], acc1[4];
    for (int m = 0; m < 4; ++m)
        for (int r = 0; r < 4; ++r) { acc0[m][r] = 0.f; acc1[m][r] = 0.f; }
#pragma unroll
    for (int s = 0; s < 4; ++s) {
        short8 b0 = *(const short8*)&BpU[((size_t)(s * 8 + 2 * w) * 64 + lane) * 8];
        short8 b1 = *(const short8*)&BpU[((size_t)(s * 8 + 2 * w + 1) * 64 + lane) * 8];
#pragma unroll
        for (int m = 0; m < 4; ++m) {
            short8 afr = *(const short8*)&At[(m * 16 + lm) * STC + s * 32 + quad * 8];
            acc0[m] = __builtin_amdgcn_mfma_f32_16x16x32_bf16(afr, b0, acc0[m], 0, 0, 0);
            acc1[m] = __builtin_amdgcn_mfma_f32_16x16x32_bf16(afr, b1, acc1[m], 0, 0, 0);
        }
    }
    // z1 = relu(U + Spq)
    for (int m = 0; m < 4; ++m)
        for (int r = 0; r < 4; ++r) {
            int rw = m * 16 + quad * 4 + r;
            acc0[m][r] = fmaxf(acc0[m][r] + bf2f(SpqB[rw * SPQ + 32 * w + lm]), 0.f);
            acc1[m][r] = fmaxf(acc1[m][r] + bf2f(SpqB[rw * SPQ + 32 * w + 16 + lm]), 0.f);
        }
    __syncthreads();
    for (int m = 0; m < 4; ++m)
        for (int r = 0; r < 4; ++r) {
            int rw = m * 16 + quad * 4 + r;
            z1[rw * STC + 32 * w + lm]      = f2bf(acc0[m][r]);
            z1[rw * STC + 32 * w + 16 + lm] = f2bf(acc1[m][r]);
        }
    __syncthreads();

    // GEMM2: z2 = relu(z1 @ Wc2 + bc2); wave w owns n-tile w; z2 overlays Spq (safe: Spq fully
    // consumed before the z1-write barrier)
    {
        f32x4 acc2[4];
        float bv = bc2[w * 16 + lm];
        for (int m = 0; m < 4; ++m)
            for (int r = 0; r < 4; ++r) acc2[m][r] = bv;
#pragma unroll
        for (int s = 0; s < 4; ++s) {
            short8 b = *(const short8*)&Bp2[((size_t)(s * 4 + w) * 64 + lane) * 8];
#pragma unroll
            for (int m = 0; m < 4; ++m) {
                short8 afr = *(const short8*)&z1[(m * 16 + lm) * STC + s * 32 + quad * 8];
                acc2[m] = __builtin_amdgcn_mfma_f32_16x16x32_bf16(afr, b, acc2[m], 0, 0, 0);
            }
        }
        for (int m = 0; m < 4; ++m)
            for (int r = 0; r < 4; ++r)
                z2[(m * 16 + quad * 4 + r) * Z2S + w * 16 + lm] = fmaxf(acc2[m][r], 0.f);
    }
    __syncthreads();

    // logits: split each 64-dot over 4 waves (wave q: c = q&1, half = q>>1)
    {
        int e = tid & 63, q = tid >> 6;
        int c = q & 1, hf = q >> 1;
        const float* zr = z2 + e * Z2S + hf * 32;
        const float* wc = Wc3 + hf * 64 + c;
        float acc = 0.f;
#pragma unroll 8
        for (int k = 0; k < 32; ++k)
            acc = fmaf(zr[k], wc[2 * k], acc);
        part[q * 64 + e] = acc;
    }
    __syncthreads();
    if (tid < 64) {
        int e = e0 + tid;
        if (e < E) {
            float l0 = bc3[0] + part[tid] + part[128 + tid];
            float l1 = bc3[1] + part[64 + tid] + part[192 + tid];
            float m = fmaxf(l0, l1);
            float lse = m + logf(expf(l0 - m) + expf(l1 - m));
            ((float2*)out)[e] = make_float2(l0 - lse, l1 - lse);
        }
    }
}

// ---------------- launch ----------------

extern "C" void kernel_launch(void* const* d_in, const int* in_sizes, int n_in,
                              void* d_out, int out_size, void* d_ws, size_t ws_size,
                              hipStream_t stream) {
    const float* x   = (const float*)d_in[0];
    const int*   ei  = (const int*)d_in[1];
    const float* ea  = (const float*)d_in[2];
    const float* W1  = (const float*)d_in[3];
    const float* b1  = (const float*)d_in[4];
    const float* W2  = (const float*)d_in[5];
    const float* b2  = (const float*)d_in[6];
    const float* W3  = (const float*)d_in[7];
    const float* b3  = (const float*)d_in[8];
    const float* We1 = (const float*)d_in[9];
    const float* be1 = (const float*)d_in[10];
    const float* We2 = (const float*)d_in[11];
    const float* be2 = (const float*)d_in[12];
    const float* Wc1 = (const float*)d_in[13];
    const float* bc1 = (const float*)d_in[14];
    const float* Wc2 = (const float*)d_in[15];
    const float* bc2 = (const float*)d_in[16];
    const float* Wc3 = (const float*)d_in[17];
    const float* bc3 = (const float*)d_in[18];
    float* out = (float*)d_out;

    int N = in_sizes[0] / 8;
    int E = in_sizes[1] / 2;
    const int* row = ei;
    const int* col = ei + E;
    int NB = (N + 1023) / 1024;

    char* w = (char*)d_ws;
    auto alloc = [&](size_t bytes) { void* p = (void*)w; w += (bytes + 255) & ~(size_t)255; return p; };
    int*   cnt       = (int*)alloc((size_t)N * 4);
    int*   col_start = (int*)alloc((size_t)(N + 1) * 4);
    int*   cursor    = (int*)alloc((size_t)N * 4);
    int*   csc_src   = (int*)alloc((size_t)E * 4);
    float* dinv      = (float*)alloc((size_t)N * 4);
    int*   bsum      = (int*)alloc(64 * 4);
    int*   boff      = (int*)alloc(64 * 4);
    float* Weff      = (float*)alloc(128 * 128 * 4);
    float* bc1p      = (float*)alloc(128 * 4);
    unsigned short* BpA  = (unsigned short*)alloc(32768);
    unsigned short* BpB  = (unsigned short*)alloc(32768);
    unsigned short* BpU  = (unsigned short*)alloc(32768);
    unsigned short* BpW2 = (unsigned short*)alloc(32768);
    unsigned short* BpW3 = (unsigned short*)alloc(32768);
    unsigned short* Bp2  = (unsigned short*)alloc(16384);
    float* aggx = (float*)alloc((size_t)N * 8 * 4);
    unsigned short* bufA = (unsigned short*)alloc((size_t)N * H * 2);
    unsigned short* bufB = (unsigned short*)alloc((size_t)N * H * 2);
    unsigned short* Pm   = (unsigned short*)alloc((size_t)N * H * 2);
    unsigned short* Qm   = (unsigned short*)alloc((size_t)N * H * 2);

    // graph build
    hipMemsetAsync(cnt, 0, (size_t)N * 4, stream);
    count_kernel<<<(E + 255) / 256, 256, 0, stream>>>(col, E, cnt);
    scan_sum_kernel<<<NB, 256, 0, stream>>>(cnt, N, bsum);
    scan_offsets_kernel<<<1, 64, 0, stream>>>(bsum, NB, boff, col_start, N);
    scan_write_kernel<<<NB, 256, 0, stream>>>(cnt, N, boff, col_start, cursor, dinv);
    scatter_kernel<<<(E + 255) / 256, 256, 0, stream>>>(row, col, E, cursor, csc_src);

    // weight prep
    weff_kernel<<<64, 256, 0, stream>>>(We2, Wc1, Weff);
    bc1p_kernel<<<1, 128, 0, stream>>>(bc1, be2, Wc1, bc1p);
    packg_kernel<<<8, 256, 0, stream>>>(Wc1, BpA);
    packg_kernel<<<8, 256, 0, stream>>>(Wc1 + 128 * 128, BpB);
    packg_kernel<<<8, 256, 0, stream>>>(Weff, BpU);
    packg_kernel<<<8, 256, 0, stream>>>(W2, BpW2);
    packg_kernel<<<8, 256, 0, stream>>>(W3, BpW3);
    pack2_kernel<<<4, 256, 0, stream>>>(Wc2, Bp2);

    // GCN: aggregate-then-transform, dinv-prescaled bf16 features
    aggx_kernel<<<(N * 8 + 255) / 256, 256, 0, stream>>>(x, col_start, csc_src, dinv, aggx, N);
    xform8bf_kernel<<<(N * 64 + 255) / 256, 256, 0, stream>>>(aggx, W1, b1, dinv,
                                                              (unsigned int*)bufA, N);  // h1d
    agg128bf_kernel<<<(N + 3) / 4, 256, 0, stream>>>((const unsigned int*)bufA, col_start, csc_src,
                                                     dinv, (unsigned int*)bufB, N);     // agg2
    xform_mfma_kernel<<<(N + 63) / 64, 256, 0, stream>>>(bufB, BpW2, b2, dinv, bufA, N); // h2d
    agg128bf_kernel<<<(N + 3) / 4, 256, 0, stream>>>((const unsigned int*)bufA, col_start, csc_src,
                                                     dinv, (unsigned int*)bufB, N);     // agg3
    xform_mfma_kernel<<<(N + 63) / 64, 256, 0, stream>>>(bufB, BpW3, b3, nullptr, bufA, N); // h3

    // node-side classifier partials (bf16)
    pq_kernel<<<(N + 63) / 64, 256, 0, stream>>>(bufA, BpA, BpB, bc1p, Pm, Qm, N);

    // fused classifier
    classifier_mfma<<<(E + 63) / 64, 256, 0, stream>>>(
        row, col, ea, We1, be1, Pm, Qm, BpU, Bp2, bc2, Wc3, bc3, out, E);
}